// Round 3
// baseline (372.518 us; speedup 1.0000x reference)
//
#include <hip/hip_runtime.h>

#define QSCALE 44.0f
#define NBLK 768
#define NTHR 256
#define NT (NBLK * NTHR)

// ---------- helpers ----------
__device__ __forceinline__ unsigned short f2bf(float f) {
    unsigned u = __float_as_uint(f);
    unsigned r = (u + 0x7fffu + ((u >> 16) & 1u)) >> 16;   // RNE
    return (unsigned short)r;
}
__device__ __forceinline__ float bfu(unsigned short s) {
    return __uint_as_float(((unsigned)s) << 16);
}

// int8 dot over one dword pair: acc += w[i] * relu(a_i + b_i)
__device__ __forceinline__ float dot4_i8(unsigned ax, unsigned bx, const float* w) {
    float acc = 0.f;
#pragma unroll
    for (int i = 0; i < 4; ++i) {
        int va = (int)(char)(ax >> (8 * i));
        int vb = (int)(char)(bx >> (8 * i));
        acc += w[i] * (float)max(va + vb, 0);
    }
    return acc;
}

// full 16-element lane dot + 8-lane reduce -> full 128-dim logit (pre-bias)
__device__ __forceinline__ float edge_dot(const uint4& a, const uint4& b, const float* w2r) {
    float acc;
    acc  = dot4_i8(a.x, b.x, w2r + 0);
    acc += dot4_i8(a.y, b.y, w2r + 4);
    acc += dot4_i8(a.z, b.z, w2r + 8);
    acc += dot4_i8(a.w, b.w, w2r + 12);
    acc += __shfl_xor(acc, 1);
    acc += __shfl_xor(acc, 2);
    acc += __shfl_xor(acc, 4);
    return acc;
}

// packed fixed-point encode: lo = ev*2^16 (u32), hi = y*ev*2^14 (i32)
__device__ __forceinline__ unsigned long long pack_contrib(float ev, float ys) {
    float flo = fminf(ev * 65536.f, 1.0e9f);
    float fhi = fmaxf(fminf(ys * ev * 16384.f, 1.0e9f), -1.0e9f);
    unsigned int qlo = (unsigned int)__float2int_rn(flo);
    int          qhi = __float2int_rn(fhi);
    return ((unsigned long long)(unsigned int)qhi << 32) | (unsigned long long)qlo;
}

// ---------- grid-wide ticket barrier (all NBLK blocks are co-resident) ----------
// bar: u64 zeroed by hipMemsetAsync before each launch; monotone within launch.
// Spin uses agent-scope atomic load (bypasses non-coherent per-XCD L2).
// __threadfence() release/acquire performs the cross-XCD L2 writeback/invalidate.
__device__ __forceinline__ void grid_sync(unsigned long long* bar) {
    __syncthreads();
    if (threadIdx.x == 0) {
        __threadfence();   // release: write back this XCD's dirty L2 lines
        unsigned long long t = atomicAdd(bar, 1ull) + 1ull;
        unsigned long long target = ((t + (unsigned long long)NBLK - 1ull)
                                     / (unsigned long long)NBLK) * (unsigned long long)NBLK;
        while (__hip_atomic_load(bar, __ATOMIC_RELAXED, __HIP_MEMORY_SCOPE_AGENT) < target)
            __builtin_amdgcn_s_sleep(2);
        __threadfence();   // acquire: invalidate stale L1/L2 lines before next phase reads
    }
    __syncthreads();
}

// ---------- fused pipeline: proj -> [sync] -> edge logits -> [sync] -> decode+alpha ----------
__global__ __launch_bounds__(NTHR) void fused_gat_kernel(
    const float* __restrict__ x, const float* __restrict__ y,
    const int* __restrict__ ei,
    const float* __restrict__ w1, const float* __restrict__ b1,
    const float* __restrict__ w2, const float* __restrict__ b2,
    unsigned char* __restrict__ P, unsigned long long* __restrict__ agg,
    unsigned long long* __restrict__ bar,
    float* __restrict__ yhat, float* __restrict__ elog, int N, int E)
{
    __shared__ unsigned short wl[64 * 256];  // 32 KB (phase 1 only)
    __shared__ float xs[32 * 64];            // 8 KB  (phase 1 only)
    const int t = threadIdx.x;
    const int gtid = blockIdx.x * NTHR + t;

    // ================= phase 1: node projection + int8 quantize + agg zero =================
    {
        for (int i = t; i < 64 * 256; i += NTHR) {
            int k = i >> 8, j = i & 255;
            float w = (j < 128) ? w1[k * 128 + j] : w1[(64 + k) * 128 + (j - 128)];
            wl[i] = f2bf(w);
        }

        const int jg = t & 63;
        const int ng = t >> 6;
        const int j0 = jg * 4;

        float bb[4] = {0.f, 0.f, 0.f, 0.f};
        if (j0 < 128) {
#pragma unroll
            for (int c = 0; c < 4; ++c) bb[c] = b1[j0 + c];
        }

        const int ntiles = (N + 31) / 32;
        for (int tile = blockIdx.x; tile < ntiles; tile += NBLK) {
            const int n0 = tile * 32;

            __syncthreads();   // protect xs from previous iteration's readers (covers wl on iter 0)
            if (t < 32) {
                int n = n0 + t;
                if (n < N) agg[n] = 0ull;
            }
            for (int i = t; i < 32 * 64; i += NTHR) {
                int n = n0 + (i >> 6);
                xs[i] = (n < N) ? x[(size_t)n * 64 + (i & 63)] : 0.f;
            }
            __syncthreads();

            float acc[8][4];
#pragma unroll
            for (int i = 0; i < 8; ++i)
#pragma unroll
                for (int c = 0; c < 4; ++c) acc[i][c] = 0.f;

            for (int k = 0; k < 64; k += 4) {
                float wv[4][4];
#pragma unroll
                for (int kk = 0; kk < 4; ++kk) {
                    ushort4 wu = *(const ushort4*)&wl[(k + kk) * 256 + j0];
                    wv[kk][0] = bfu(wu.x); wv[kk][1] = bfu(wu.y);
                    wv[kk][2] = bfu(wu.z); wv[kk][3] = bfu(wu.w);
                }
#pragma unroll
                for (int i = 0; i < 8; ++i) {
                    const float4 xv = *(const float4*)&xs[(ng * 8 + i) * 64 + k];
#pragma unroll
                    for (int c = 0; c < 4; ++c)
                        acc[i][c] += xv.x * wv[0][c] + xv.y * wv[1][c] + xv.z * wv[2][c] + xv.w * wv[3][c];
                }
            }

#pragma unroll
            for (int i = 0; i < 8; ++i) {
                int n = n0 + ng * 8 + i;
                if (n < N) {
                    unsigned pk = 0;
#pragma unroll
                    for (int c = 0; c < 4; ++c) {
                        float v = (acc[i][c] + bb[c]) * QSCALE;
                        int q = __float2int_rn(fminf(fmaxf(v, -127.f), 127.f));
                        pk |= ((unsigned)(q & 0xff)) << (8 * c);
                    }
                    *(unsigned*)(P + (size_t)n * 256 + j0) = pk;
                }
            }
        }
    }

    grid_sync(bar);

    // ================= phase 2: edge logits + packed atomic aggregation =================
    {
        const int lane = t & 7;
        float w2r[16];
#pragma unroll
        for (int c = 0; c < 16; ++c) w2r[c] = w2[lane * 16 + c] * (1.0f / QSCALE);
        const float b2s = b2[0];

        const int slot = gtid >> 3;
        const int nslots = NT >> 3;
        const int lo16 = lane * 16;

        for (int base = slot * 4; base < E; base += nslots * 4) {
            if (base + 3 < E) {
                const int4 s4 = *(const int4*)&ei[base];
                const int4 d4 = *(const int4*)&ei[E + base];

                const uint4 a0 = *(const uint4*)(P + (size_t)s4.x * 256 + lo16);
                const uint4 b0 = *(const uint4*)(P + (size_t)d4.x * 256 + 128 + lo16);
                const uint4 a1 = *(const uint4*)(P + (size_t)s4.y * 256 + lo16);
                const uint4 b1v = *(const uint4*)(P + (size_t)d4.y * 256 + 128 + lo16);
                const uint4 a2 = *(const uint4*)(P + (size_t)s4.z * 256 + lo16);
                const uint4 b2v = *(const uint4*)(P + (size_t)d4.z * 256 + 128 + lo16);
                const uint4 a3 = *(const uint4*)(P + (size_t)s4.w * 256 + lo16);
                const uint4 b3 = *(const uint4*)(P + (size_t)d4.w * 256 + 128 + lo16);

                const float acc0 = edge_dot(a0, b0, w2r);
                const float acc1 = edge_dot(a1, b1v, w2r);
                const float acc2 = edge_dot(a2, b2v, w2r);
                const float acc3 = edge_dot(a3, b3, w2r);

                if (lane == 0) {
                    const float ys0 = y[s4.x];
                    const float ys1 = y[s4.y];
                    const float ys2 = y[s4.z];
                    const float ys3 = y[s4.w];
                    const float ev0 = __expf(acc0 + b2s);
                    const float ev1 = __expf(acc1 + b2s);
                    const float ev2 = __expf(acc2 + b2s);
                    const float ev3 = __expf(acc3 + b2s);
                    *(float4*)&elog[base] = make_float4(ev0, ev1, ev2, ev3);
                    atomicAdd(&agg[d4.x], pack_contrib(ev0, ys0));
                    atomicAdd(&agg[d4.y], pack_contrib(ev1, ys1));
                    atomicAdd(&agg[d4.z], pack_contrib(ev2, ys2));
                    atomicAdd(&agg[d4.w], pack_contrib(ev3, ys3));
                }
            } else {
                for (int e = base; e < E; ++e) {
                    const int s = ei[e];
                    const int d = ei[E + e];
                    const uint4 a = *(const uint4*)(P + (size_t)s * 256 + lo16);
                    const uint4 b = *(const uint4*)(P + (size_t)d * 256 + 128 + lo16);
                    const float acc = edge_dot(a, b, w2r);
                    if (lane == 0) {
                        const float ev = __expf(acc + b2s);
                        elog[e] = ev;
                        atomicAdd(&agg[d], pack_contrib(ev, y[s]));
                    }
                }
            }
        }
    }

    grid_sync(bar);

    // ================= phase 3: node decode (yhat) + alpha normalize, fused =================
    {
        for (int i = gtid; i < N; i += NT) {
            unsigned long long v = agg[i];
            unsigned int lo = (unsigned int)(v & 0xffffffffull);
            int          hi = (int)(v >> 32);
            yhat[i] = (lo != 0u) ? 4.0f * (float)hi / (float)lo : 0.f;   // (hi/2^14)/(lo/2^16)
        }

        for (int base = gtid * 4; base < E; base += NT * 4) {
            if (base + 3 < E) {
                const int4 d4 = *(const int4*)&ei[E + base];
                float4 ev4 = *(const float4*)&elog[base];
                const unsigned int l0 = (unsigned int)(agg[d4.x] & 0xffffffffull);
                const unsigned int l1 = (unsigned int)(agg[d4.y] & 0xffffffffull);
                const unsigned int l2 = (unsigned int)(agg[d4.z] & 0xffffffffull);
                const unsigned int l3 = (unsigned int)(agg[d4.w] & 0xffffffffull);
                ev4.x = l0 ? ev4.x * (65536.0f / (float)l0) : 0.f;
                ev4.y = l1 ? ev4.y * (65536.0f / (float)l1) : 0.f;
                ev4.z = l2 ? ev4.z * (65536.0f / (float)l2) : 0.f;
                ev4.w = l3 ? ev4.w * (65536.0f / (float)l3) : 0.f;
                *(float4*)&elog[base] = ev4;
            } else {
                for (int e = base; e < E; ++e) {
                    const unsigned int lo = (unsigned int)(agg[ei[E + e]] & 0xffffffffull);
                    elog[e] = lo ? elog[e] * (65536.0f / (float)lo) : 0.f;
                }
            }
        }
    }
}

extern "C" void kernel_launch(void* const* d_in, const int* in_sizes, int n_in,
                              void* d_out, int out_size, void* d_ws, size_t ws_size,
                              hipStream_t stream) {
    const float* x  = (const float*)d_in[0];
    const float* y  = (const float*)d_in[1];
    const int*   ei = (const int*)d_in[2];
    const float* w1 = (const float*)d_in[3];
    const float* b1 = (const float*)d_in[4];
    const float* w2 = (const float*)d_in[5];
    const float* b2 = (const float*)d_in[6];

    const int N = in_sizes[1];
    const int E = in_sizes[2] / 2;

    float* out  = (float*)d_out;
    float* yhat = out;          // [N]
    float* elog = out + N;      // [E] — exp values, then alpha in place

    char* ws = (char*)d_ws;
    unsigned long long* bar = (unsigned long long*)ws;             // 1 u64 (pad to 256B)
    unsigned char* P = (unsigned char*)(ws + 256);                 // N*256 int8 = 12.8 MB
    const size_t Pbytes = (size_t)N * 256;
    unsigned long long* agg = (unsigned long long*)(ws + 256 + Pbytes);  // N u64

    hipMemsetAsync(bar, 0, 8, stream);   // stream op: graph-capture-safe
    fused_gat_kernel<<<NBLK, NTHR, 0, stream>>>(
        x, y, ei, w1, b1, w2, b2, P, agg, bar, yhat, elog, N, E);
}

// Round 5
// 310.382 us; speedup vs baseline: 1.2002x; 1.2002x over previous
//
#include <hip/hip_runtime.h>

#define QSCALE 44.0f
#define NBLK2 768           // persistent fused kernel: 3 blocks/CU — hardware-proven co-resident (R3)
#define NTHR 256
#define NT2 (NBLK2 * NTHR)

// ---------- helpers ----------
__device__ __forceinline__ unsigned short f2bf(float f) {
    unsigned u = __float_as_uint(f);
    unsigned r = (u + 0x7fffu + ((u >> 16) & 1u)) >> 16;   // RNE
    return (unsigned short)r;
}
__device__ __forceinline__ float bfu(unsigned short s) {
    return __uint_as_float(((unsigned)s) << 16);
}

// int8 dot over one dword pair: acc += w[i] * relu(a_i + b_i)
__device__ __forceinline__ float dot4_i8(unsigned ax, unsigned bx, const float* w) {
    float acc = 0.f;
#pragma unroll
    for (int i = 0; i < 4; ++i) {
        int va = (int)(char)(ax >> (8 * i));
        int vb = (int)(char)(bx >> (8 * i));
        acc += w[i] * (float)max(va + vb, 0);
    }
    return acc;
}

// full 16-element lane dot + 8-lane reduce -> full 128-dim logit (pre-bias)
__device__ __forceinline__ float edge_dot(const uint4& a, const uint4& b, const float* w2r) {
    float acc;
    acc  = dot4_i8(a.x, b.x, w2r + 0);
    acc += dot4_i8(a.y, b.y, w2r + 4);
    acc += dot4_i8(a.z, b.z, w2r + 8);
    acc += dot4_i8(a.w, b.w, w2r + 12);
    acc += __shfl_xor(acc, 1);
    acc += __shfl_xor(acc, 2);
    acc += __shfl_xor(acc, 4);
    return acc;
}

// packed fixed-point encode: lo = ev*2^16 (u32), hi = y*ev*2^14 (i32)
__device__ __forceinline__ unsigned long long pack_contrib(float ev, float ys) {
    float flo = fminf(ev * 65536.f, 1.0e9f);
    float fhi = fmaxf(fminf(ys * ev * 16384.f, 1.0e9f), -1.0e9f);
    unsigned int qlo = (unsigned int)__float2int_rn(flo);
    int          qhi = __float2int_rn(fhi);
    return ((unsigned long long)(unsigned int)qhi << 32) | (unsigned long long)qlo;
}

// ---------- grid-wide ticket barrier (R3-proven correct at 768 blocks) ----------
__device__ __forceinline__ void grid_sync(unsigned long long* bar) {
    __syncthreads();
    if (threadIdx.x == 0) {
        __threadfence();   // release: write back this XCD's dirty L2 lines
        unsigned long long t = atomicAdd(bar, 1ull) + 1ull;
        unsigned long long target = ((t + (unsigned long long)NBLK2 - 1ull)
                                     / (unsigned long long)NBLK2) * (unsigned long long)NBLK2;
        while (__hip_atomic_load(bar, __ATOMIC_RELAXED, __HIP_MEMORY_SCOPE_AGENT) < target)
            __builtin_amdgcn_s_sleep(2);
        __threadfence();   // acquire: invalidate stale lines before next phase reads
    }
    __syncthreads();
}

// ---------- kernel 1: persistent node projection + int8 quantize + agg zero ----------
// grid 1024: 4 blk/CU (4 x 40KB = 160KB LDS exactly), critical path 2 tiles/block.
__global__ __launch_bounds__(256) void proj_kernel(
    const float* __restrict__ x, const float* __restrict__ w1, const float* __restrict__ b1,
    unsigned char* __restrict__ P, unsigned long long* __restrict__ agg, int N)
{
    __shared__ unsigned short wl[64 * 256];  // 32 KB, persistent across tiles
    __shared__ float xs[32 * 64];            // 8 KB, reloaded per tile
    const int t = threadIdx.x;

    for (int i = t; i < 64 * 256; i += 256) {
        int k = i >> 8, j = i & 255;
        float w = (j < 128) ? w1[k * 128 + j] : w1[(64 + k) * 128 + (j - 128)];
        wl[i] = f2bf(w);
    }

    const int jg = t & 63;
    const int ng = t >> 6;
    const int j0 = jg * 4;

    float bb[4] = {0.f, 0.f, 0.f, 0.f};
    if (j0 < 128) {
#pragma unroll
        for (int c = 0; c < 4; ++c) bb[c] = b1[j0 + c];
    }

    const int ntiles = (N + 31) / 32;
    for (int tile = blockIdx.x; tile < ntiles; tile += gridDim.x) {
        const int n0 = tile * 32;

        __syncthreads();   // protect xs from previous iteration's readers (covers wl on iter 0)
        if (t < 32) {
            int n = n0 + t;
            if (n < N) agg[n] = 0ull;
        }
        for (int i = t; i < 32 * 64; i += 256) {
            int n = n0 + (i >> 6);
            xs[i] = (n < N) ? x[(size_t)n * 64 + (i & 63)] : 0.f;
        }
        __syncthreads();

        float acc[8][4];
#pragma unroll
        for (int i = 0; i < 8; ++i)
#pragma unroll
            for (int c = 0; c < 4; ++c) acc[i][c] = 0.f;

        for (int k = 0; k < 64; k += 4) {
            float wv[4][4];
#pragma unroll
            for (int kk = 0; kk < 4; ++kk) {
                ushort4 wu = *(const ushort4*)&wl[(k + kk) * 256 + j0];
                wv[kk][0] = bfu(wu.x); wv[kk][1] = bfu(wu.y);
                wv[kk][2] = bfu(wu.z); wv[kk][3] = bfu(wu.w);
            }
#pragma unroll
            for (int i = 0; i < 8; ++i) {
                const float4 xv = *(const float4*)&xs[(ng * 8 + i) * 64 + k];
#pragma unroll
                for (int c = 0; c < 4; ++c)
                    acc[i][c] += xv.x * wv[0][c] + xv.y * wv[1][c] + xv.z * wv[2][c] + xv.w * wv[3][c];
            }
        }

#pragma unroll
        for (int i = 0; i < 8; ++i) {
            int n = n0 + ng * 8 + i;
            if (n < N) {
                unsigned pk = 0;
#pragma unroll
                for (int c = 0; c < 4; ++c) {
                    float v = (acc[i][c] + bb[c]) * QSCALE;
                    int q = __float2int_rn(fminf(fmaxf(v, -127.f), 127.f));
                    pk |= ((unsigned)(q & 0xff)) << (8 * c);
                }
                *(unsigned*)(P + (size_t)n * 256 + j0) = pk;
            }
        }
    }
}

// ---------- kernel 2: persistent edge logits + atomic agg -> [grid sync] -> decode + alpha ----------
// Zero LDS so the edge phase keeps its native occupancy. 768 blocks = 3/CU: co-resident
// for any VGPR count <= 128, no forced spills needed.
__global__ __launch_bounds__(NTHR) void edge_fused_kernel(
    const unsigned char* __restrict__ P, const int* __restrict__ ei,
    const float* __restrict__ y,
    const float* __restrict__ w2, const float* __restrict__ b2,
    float* __restrict__ elog, unsigned long long* __restrict__ agg,
    unsigned long long* __restrict__ bar, float* __restrict__ yhat,
    int N, int E)
{
    const int t = threadIdx.x;
    const int gtid = blockIdx.x * NTHR + t;

    // ===== phase A: edge logits + packed atomic aggregation (R2-proven form) =====
    {
        const int lane = t & 7;
        float w2r[16];
#pragma unroll
        for (int c = 0; c < 16; ++c) w2r[c] = w2[lane * 16 + c] * (1.0f / QSCALE);
        const float b2s = b2[0];

        const int slot = gtid >> 3;
        const int nslots = NT2 >> 3;
        const int lo16 = lane * 16;

        for (int base = slot * 4; base < E; base += nslots * 4) {
            if (base + 3 < E) {
                const int4 s4 = *(const int4*)&ei[base];
                const int4 d4 = *(const int4*)&ei[E + base];

                const uint4 a0 = *(const uint4*)(P + (size_t)s4.x * 256 + lo16);
                const uint4 b0 = *(const uint4*)(P + (size_t)d4.x * 256 + 128 + lo16);
                const uint4 a1 = *(const uint4*)(P + (size_t)s4.y * 256 + lo16);
                const uint4 b1v = *(const uint4*)(P + (size_t)d4.y * 256 + 128 + lo16);
                const uint4 a2 = *(const uint4*)(P + (size_t)s4.z * 256 + lo16);
                const uint4 b2v = *(const uint4*)(P + (size_t)d4.z * 256 + 128 + lo16);
                const uint4 a3 = *(const uint4*)(P + (size_t)s4.w * 256 + lo16);
                const uint4 b3 = *(const uint4*)(P + (size_t)d4.w * 256 + 128 + lo16);

                const float acc0 = edge_dot(a0, b0, w2r);
                const float acc1 = edge_dot(a1, b1v, w2r);
                const float acc2 = edge_dot(a2, b2v, w2r);
                const float acc3 = edge_dot(a3, b3, w2r);

                if (lane == 0) {
                    const float ys0 = y[s4.x];
                    const float ys1 = y[s4.y];
                    const float ys2 = y[s4.z];
                    const float ys3 = y[s4.w];
                    const float ev0 = __expf(acc0 + b2s);
                    const float ev1 = __expf(acc1 + b2s);
                    const float ev2 = __expf(acc2 + b2s);
                    const float ev3 = __expf(acc3 + b2s);
                    *(float4*)&elog[base] = make_float4(ev0, ev1, ev2, ev3);
                    atomicAdd(&agg[d4.x], pack_contrib(ev0, ys0));
                    atomicAdd(&agg[d4.y], pack_contrib(ev1, ys1));
                    atomicAdd(&agg[d4.z], pack_contrib(ev2, ys2));
                    atomicAdd(&agg[d4.w], pack_contrib(ev3, ys3));
                }
            } else {
                for (int e = base; e < E; ++e) {
                    const int s = ei[e];
                    const int d = ei[E + e];
                    const uint4 a = *(const uint4*)(P + (size_t)s * 256 + lo16);
                    const uint4 b = *(const uint4*)(P + (size_t)d * 256 + 128 + lo16);
                    const float acc = edge_dot(a, b, w2r);
                    if (lane == 0) {
                        const float ev = __expf(acc + b2s);
                        elog[e] = ev;
                        atomicAdd(&agg[d], pack_contrib(ev, y[s]));
                    }
                }
            }
        }
    }

    grid_sync(bar);

    // ===== phase B: node decode (yhat) + alpha normalize, agg read inline =====
    {
        for (int i = gtid; i < N; i += NT2) {
            unsigned long long v = agg[i];
            unsigned int lo = (unsigned int)(v & 0xffffffffull);
            int          hi = (int)(v >> 32);
            yhat[i] = (lo != 0u) ? 4.0f * (float)hi / (float)lo : 0.f;   // (hi/2^14)/(lo/2^16)
        }

        for (int base = gtid * 4; base < E; base += NT2 * 4) {
            if (base + 3 < E) {
                const int4 d4 = *(const int4*)&ei[E + base];
                float4 ev4 = *(const float4*)&elog[base];
                const unsigned int l0 = (unsigned int)(agg[d4.x] & 0xffffffffull);
                const unsigned int l1 = (unsigned int)(agg[d4.y] & 0xffffffffull);
                const unsigned int l2 = (unsigned int)(agg[d4.z] & 0xffffffffull);
                const unsigned int l3 = (unsigned int)(agg[d4.w] & 0xffffffffull);
                ev4.x = l0 ? ev4.x * (65536.0f / (float)l0) : 0.f;
                ev4.y = l1 ? ev4.y * (65536.0f / (float)l1) : 0.f;
                ev4.z = l2 ? ev4.z * (65536.0f / (float)l2) : 0.f;
                ev4.w = l3 ? ev4.w * (65536.0f / (float)l3) : 0.f;
                *(float4*)&elog[base] = ev4;
            } else {
                for (int e = base; e < E; ++e) {
                    const unsigned int lo = (unsigned int)(agg[ei[E + e]] & 0xffffffffull);
                    elog[e] = lo ? elog[e] * (65536.0f / (float)lo) : 0.f;
                }
            }
        }
    }
}

extern "C" void kernel_launch(void* const* d_in, const int* in_sizes, int n_in,
                              void* d_out, int out_size, void* d_ws, size_t ws_size,
                              hipStream_t stream) {
    const float* x  = (const float*)d_in[0];
    const float* y  = (const float*)d_in[1];
    const int*   ei = (const int*)d_in[2];
    const float* w1 = (const float*)d_in[3];
    const float* b1 = (const float*)d_in[4];
    const float* w2 = (const float*)d_in[5];
    const float* b2 = (const float*)d_in[6];

    const int N = in_sizes[1];
    const int E = in_sizes[2] / 2;

    float* out  = (float*)d_out;
    float* yhat = out;          // [N]
    float* elog = out + N;      // [E] — exp values, then alpha in place

    char* ws = (char*)d_ws;
    unsigned long long* bar = (unsigned long long*)ws;                   // 1 u64 (padded)
    unsigned char* P = (unsigned char*)(ws + 256);                       // N*256 int8
    const size_t Pbytes = (size_t)N * 256;
    unsigned long long* agg = (unsigned long long*)(ws + 256 + Pbytes);  // N u64

    hipMemsetAsync(bar, 0, 8, stream);   // stream op: graph-capture-safe
    proj_kernel<<<1024, 256, 0, stream>>>(x, w1, b1, P, agg, N);
    edge_fused_kernel<<<NBLK2, NTHR, 0, stream>>>(P, ei, y, w2, b2, elog, agg, bar, yhat, N, E);
}

// Round 6
// 208.776 us; speedup vs baseline: 1.7843x; 1.4867x over previous
//
#include <hip/hip_runtime.h>

#define QSCALE 44.0f

// ---------- helpers ----------
__device__ __forceinline__ unsigned short f2bf(float f) {
    unsigned u = __float_as_uint(f);
    unsigned r = (u + 0x7fffu + ((u >> 16) & 1u)) >> 16;   // RNE
    return (unsigned short)r;
}
__device__ __forceinline__ float bfu(unsigned short s) {
    return __uint_as_float(((unsigned)s) << 16);
}

// int8 dot over one dword pair: acc += w[i] * relu(a_i + b_i)
__device__ __forceinline__ float dot4_i8(unsigned ax, unsigned bx, const float* w) {
    float acc = 0.f;
#pragma unroll
    for (int i = 0; i < 4; ++i) {
        int va = (int)(char)(ax >> (8 * i));
        int vb = (int)(char)(bx >> (8 * i));
        acc += w[i] * (float)max(va + vb, 0);
    }
    return acc;
}

// full 16-element lane dot + 8-lane reduce -> full 128-dim logit (pre-bias)
__device__ __forceinline__ float edge_dot(const uint4& a, const uint4& b, const float* w2r) {
    float acc;
    acc  = dot4_i8(a.x, b.x, w2r + 0);
    acc += dot4_i8(a.y, b.y, w2r + 4);
    acc += dot4_i8(a.z, b.z, w2r + 8);
    acc += dot4_i8(a.w, b.w, w2r + 12);
    acc += __shfl_xor(acc, 1);
    acc += __shfl_xor(acc, 2);
    acc += __shfl_xor(acc, 4);
    return acc;
}

// packed fixed-point encode: lo = ev*2^16 (u32), hi = y*ev*2^14 (i32)
__device__ __forceinline__ unsigned long long pack_contrib(float ev, float ys) {
    float flo = fminf(ev * 65536.f, 1.0e9f);
    float fhi = fmaxf(fminf(ys * ev * 16384.f, 1.0e9f), -1.0e9f);
    unsigned int qlo = (unsigned int)__float2int_rn(flo);
    int          qhi = __float2int_rn(fhi);
    return ((unsigned long long)(unsigned int)qhi << 32) | (unsigned long long)qlo;
}

// ---------- kernel 1: persistent node projection + int8 quantize + agg zero ----------
// grid 768: 3 blk/CU (120 KB LDS of 160 — guaranteed resident), critical path 3 tiles.
__global__ __launch_bounds__(256) void proj_kernel(
    const float* __restrict__ x, const float* __restrict__ w1, const float* __restrict__ b1,
    unsigned char* __restrict__ P, unsigned long long* __restrict__ agg, int N)
{
    __shared__ unsigned short wl[64 * 256];  // 32 KB, persistent across tiles
    __shared__ float xs[32 * 64];            // 8 KB, reloaded per tile
    const int t = threadIdx.x;

    for (int i = t; i < 64 * 256; i += 256) {
        int k = i >> 8, j = i & 255;
        float w = (j < 128) ? w1[k * 128 + j] : w1[(64 + k) * 128 + (j - 128)];
        wl[i] = f2bf(w);
    }

    const int jg = t & 63;
    const int ng = t >> 6;
    const int j0 = jg * 4;

    float bb[4] = {0.f, 0.f, 0.f, 0.f};
    if (j0 < 128) {
#pragma unroll
        for (int c = 0; c < 4; ++c) bb[c] = b1[j0 + c];
    }

    const int ntiles = (N + 31) / 32;
    for (int tile = blockIdx.x; tile < ntiles; tile += gridDim.x) {
        const int n0 = tile * 32;

        __syncthreads();   // protect xs from previous iteration's readers (covers wl on iter 0)
        if (t < 32) {
            int n = n0 + t;
            if (n < N) agg[n] = 0ull;
        }
        for (int i = t; i < 32 * 64; i += 256) {
            int n = n0 + (i >> 6);
            xs[i] = (n < N) ? x[(size_t)n * 64 + (i & 63)] : 0.f;
        }
        __syncthreads();

        float acc[8][4];
#pragma unroll
        for (int i = 0; i < 8; ++i)
#pragma unroll
            for (int c = 0; c < 4; ++c) acc[i][c] = 0.f;

        for (int k = 0; k < 64; k += 4) {
            float wv[4][4];
#pragma unroll
            for (int kk = 0; kk < 4; ++kk) {
                ushort4 wu = *(const ushort4*)&wl[(k + kk) * 256 + j0];
                wv[kk][0] = bfu(wu.x); wv[kk][1] = bfu(wu.y);
                wv[kk][2] = bfu(wu.z); wv[kk][3] = bfu(wu.w);
            }
#pragma unroll
            for (int i = 0; i < 8; ++i) {
                const float4 xv = *(const float4*)&xs[(ng * 8 + i) * 64 + k];
#pragma unroll
                for (int c = 0; c < 4; ++c)
                    acc[i][c] += xv.x * wv[0][c] + xv.y * wv[1][c] + xv.z * wv[2][c] + xv.w * wv[3][c];
            }
        }

#pragma unroll
        for (int i = 0; i < 8; ++i) {
            int n = n0 + ng * 8 + i;
            if (n < N) {
                unsigned pk = 0;
#pragma unroll
                for (int c = 0; c < 4; ++c) {
                    float v = (acc[i][c] + bb[c]) * QSCALE;
                    int q = __float2int_rn(fminf(fmaxf(v, -127.f), 127.f));
                    pk |= ((unsigned)(q & 0xff)) << (8 * c);
                }
                *(unsigned*)(P + (size_t)n * 256 + j0) = pk;
            }
        }
    }
}

// ---------- kernel 2: edge logit (R2-proven exact form, 2048 blocks) ----------
__global__ __launch_bounds__(256) void edge_logit_kernel(
    const unsigned char* __restrict__ P, const int* __restrict__ ei,
    const float* __restrict__ y,
    const float* __restrict__ w2, const float* __restrict__ b2,
    float* __restrict__ elog, unsigned long long* __restrict__ agg, int E)
{
    const int lane = threadIdx.x & 7;
    float w2r[16];
#pragma unroll
    for (int c = 0; c < 16; ++c) w2r[c] = w2[lane * 16 + c] * (1.0f / QSCALE);
    const float b2s = b2[0];

    const int slot = (blockIdx.x * 256 + threadIdx.x) >> 3;
    const int nslots = (gridDim.x * 256) >> 3;
    const int lo16 = lane * 16;

    for (int base = slot * 4; base < E; base += nslots * 4) {
        if (base + 3 < E) {
            const int4 s4 = *(const int4*)&ei[base];
            const int4 d4 = *(const int4*)&ei[E + base];

            const uint4 a0 = *(const uint4*)(P + (size_t)s4.x * 256 + lo16);
            const uint4 b0 = *(const uint4*)(P + (size_t)d4.x * 256 + 128 + lo16);
            const uint4 a1 = *(const uint4*)(P + (size_t)s4.y * 256 + lo16);
            const uint4 b1v = *(const uint4*)(P + (size_t)d4.y * 256 + 128 + lo16);
            const uint4 a2 = *(const uint4*)(P + (size_t)s4.z * 256 + lo16);
            const uint4 b2v = *(const uint4*)(P + (size_t)d4.z * 256 + 128 + lo16);
            const uint4 a3 = *(const uint4*)(P + (size_t)s4.w * 256 + lo16);
            const uint4 b3 = *(const uint4*)(P + (size_t)d4.w * 256 + 128 + lo16);

            const float acc0 = edge_dot(a0, b0, w2r);
            const float acc1 = edge_dot(a1, b1v, w2r);
            const float acc2 = edge_dot(a2, b2v, w2r);
            const float acc3 = edge_dot(a3, b3, w2r);

            if (lane == 0) {
                const float ys0 = y[s4.x];
                const float ys1 = y[s4.y];
                const float ys2 = y[s4.z];
                const float ys3 = y[s4.w];
                const float ev0 = __expf(acc0 + b2s);
                const float ev1 = __expf(acc1 + b2s);
                const float ev2 = __expf(acc2 + b2s);
                const float ev3 = __expf(acc3 + b2s);
                *(float4*)&elog[base] = make_float4(ev0, ev1, ev2, ev3);
                atomicAdd(&agg[d4.x], pack_contrib(ev0, ys0));
                atomicAdd(&agg[d4.y], pack_contrib(ev1, ys1));
                atomicAdd(&agg[d4.z], pack_contrib(ev2, ys2));
                atomicAdd(&agg[d4.w], pack_contrib(ev3, ys3));
            }
        } else {
            for (int e = base; e < E; ++e) {
                const int s = ei[e];
                const int d = ei[E + e];
                const uint4 a = *(const uint4*)(P + (size_t)s * 256 + lo16);
                const uint4 b = *(const uint4*)(P + (size_t)d * 256 + 128 + lo16);
                const float acc = edge_dot(a, b, w2r);
                if (lane == 0) {
                    const float ev = __expf(acc + b2s);
                    elog[e] = ev;
                    atomicAdd(&agg[d], pack_contrib(ev, y[s]));
                }
            }
        }
    }
}

// ---------- kernel 3: fused decode (yhat) + alpha normalize, agg read directly ----------
__global__ __launch_bounds__(256) void decode_alpha_kernel(
    const int* __restrict__ ei, const unsigned long long* __restrict__ agg,
    float* __restrict__ elog, float* __restrict__ yhat, int N, int E)
{
    const int gtid = blockIdx.x * 256 + threadIdx.x;
    const int ntot = gridDim.x * 256;

    for (int i = gtid; i < N; i += ntot) {
        unsigned long long v = agg[i];
        unsigned int lo = (unsigned int)(v & 0xffffffffull);
        int          hi = (int)(v >> 32);
        yhat[i] = (lo != 0u) ? 4.0f * (float)hi / (float)lo : 0.f;   // (hi/2^14)/(lo/2^16)
    }

    for (int base = gtid * 4; base < E; base += ntot * 4) {
        if (base + 3 < E) {
            const int4 d4 = *(const int4*)&ei[E + base];
            float4 ev4 = *(const float4*)&elog[base];
            const unsigned int l0 = (unsigned int)(agg[d4.x] & 0xffffffffull);
            const unsigned int l1 = (unsigned int)(agg[d4.y] & 0xffffffffull);
            const unsigned int l2 = (unsigned int)(agg[d4.z] & 0xffffffffull);
            const unsigned int l3 = (unsigned int)(agg[d4.w] & 0xffffffffull);
            ev4.x = l0 ? ev4.x * (65536.0f / (float)l0) : 0.f;
            ev4.y = l1 ? ev4.y * (65536.0f / (float)l1) : 0.f;
            ev4.z = l2 ? ev4.z * (65536.0f / (float)l2) : 0.f;
            ev4.w = l3 ? ev4.w * (65536.0f / (float)l3) : 0.f;
            *(float4*)&elog[base] = ev4;
        } else {
            for (int e = base; e < E; ++e) {
                const unsigned int lo = (unsigned int)(agg[ei[E + e]] & 0xffffffffull);
                elog[e] = lo ? elog[e] * (65536.0f / (float)lo) : 0.f;
            }
        }
    }
}

extern "C" void kernel_launch(void* const* d_in, const int* in_sizes, int n_in,
                              void* d_out, int out_size, void* d_ws, size_t ws_size,
                              hipStream_t stream) {
    const float* x  = (const float*)d_in[0];
    const float* y  = (const float*)d_in[1];
    const int*   ei = (const int*)d_in[2];
    const float* w1 = (const float*)d_in[3];
    const float* b1 = (const float*)d_in[4];
    const float* w2 = (const float*)d_in[5];
    const float* b2 = (const float*)d_in[6];

    const int N = in_sizes[1];
    const int E = in_sizes[2] / 2;

    float* out  = (float*)d_out;
    float* yhat = out;          // [N]
    float* elog = out + N;      // [E] — exp values, then alpha in place

    char* ws = (char*)d_ws;
    unsigned char* P = (unsigned char*)ws;                         // N*256 int8 = 12.8 MB
    const size_t Pbytes = (size_t)N * 256;
    unsigned long long* agg = (unsigned long long*)(ws + Pbytes);  // N u64

    proj_kernel<<<768, 256, 0, stream>>>(x, w1, b1, P, agg, N);
    edge_logit_kernel<<<2048, 256, 0, stream>>>(P, ei, y, w2, b2, elog, agg, E);
    decode_alpha_kernel<<<1600, 256, 0, stream>>>(ei, agg, elog, yhat, N, E);
}

// Round 7
// 208.646 us; speedup vs baseline: 1.7854x; 1.0006x over previous
//
#include <hip/hip_runtime.h>

#define QSCALE 44.0f
#define PTILE 64

// ---------- helpers ----------
__device__ __forceinline__ unsigned short f2bf(float f) {
    unsigned u = __float_as_uint(f);
    unsigned r = (u + 0x7fffu + ((u >> 16) & 1u)) >> 16;   // RNE
    return (unsigned short)r;
}
__device__ __forceinline__ float bfu(unsigned short s) {
    return __uint_as_float(((unsigned)s) << 16);
}

// int8 dot over one dword pair: acc += w[i] * relu(a_i + b_i)
__device__ __forceinline__ float dot4_i8(unsigned ax, unsigned bx, const float* w) {
    float acc = 0.f;
#pragma unroll
    for (int i = 0; i < 4; ++i) {
        int va = (int)(char)(ax >> (8 * i));
        int vb = (int)(char)(bx >> (8 * i));
        acc += w[i] * (float)max(va + vb, 0);
    }
    return acc;
}

// full 16-element lane dot + 8-lane reduce -> full 128-dim logit (pre-bias)
__device__ __forceinline__ float edge_dot(const uint4& a, const uint4& b, const float* w2r) {
    float acc;
    acc  = dot4_i8(a.x, b.x, w2r + 0);
    acc += dot4_i8(a.y, b.y, w2r + 4);
    acc += dot4_i8(a.z, b.z, w2r + 8);
    acc += dot4_i8(a.w, b.w, w2r + 12);
    acc += __shfl_xor(acc, 1);
    acc += __shfl_xor(acc, 2);
    acc += __shfl_xor(acc, 4);
    return acc;
}

// packed fixed-point encode: lo = ev*2^16 (u32), hi = y*ev*2^14 (i32)
__device__ __forceinline__ unsigned long long pack_contrib(float ev, float ys) {
    float flo = fminf(ev * 65536.f, 1.0e9f);
    float fhi = fmaxf(fminf(ys * ev * 16384.f, 1.0e9f), -1.0e9f);
    unsigned int qlo = (unsigned int)__float2int_rn(flo);
    int          qhi = __float2int_rn(fhi);
    return ((unsigned long long)(unsigned int)qhi << 32) | (unsigned long long)qlo;
}

// ---------- kernel 1: node projection v2 — one 64-node tile per block, 8x8 accumulator ----------
// 256 threads: jg = t&31 -> 8 output cols, ng = t>>5 -> 8 node rows. acc[8][8].
// Per k-group: 8 LDS w-reads + 8 LDS x-broadcasts feed 256 FMA (21 FMA/read, 2x the old 8x4 form).
// LDS 48 KB -> 3 blocks/CU; grid 782 = 1 tile/block (14 blocks take a 2nd tile).
__global__ __launch_bounds__(256) void proj_kernel(
    const float* __restrict__ x, const float* __restrict__ w1, const float* __restrict__ b1,
    unsigned char* __restrict__ P, unsigned long long* __restrict__ agg, int N)
{
    __shared__ unsigned short wl[64 * 256];   // 32 KB bf16 weights: [k][j], j<128 top-half, j>=128 bottom-half
    __shared__ float xs[PTILE * 64];          // 16 KB
    const int t = threadIdx.x;

    for (int i = t; i < 64 * 256; i += 256) {
        int k = i >> 8, j = i & 255;
        float w = (j < 128) ? w1[k * 128 + j] : w1[(64 + k) * 128 + (j - 128)];
        wl[i] = f2bf(w);
    }

    const int jg = t & 31;
    const int ng = t >> 5;
    const int j0 = jg * 8;            // multiple of 8; group entirely <128 or >=128

    float bb[8];
#pragma unroll
    for (int c = 0; c < 8; ++c) bb[c] = 0.f;
    if (j0 < 128) {
#pragma unroll
        for (int c = 0; c < 8; ++c) bb[c] = b1[j0 + c];
    }

    const int ntiles = (N + PTILE - 1) / PTILE;
    for (int tile = blockIdx.x; tile < ntiles; tile += gridDim.x) {
        const int n0 = tile * PTILE;

        __syncthreads();   // protect xs from previous iteration's readers (covers wl on iter 0)
        if (t < PTILE) {
            int n = n0 + t;
            if (n < N) agg[n] = 0ull;
        }
        // stage x: 64 rows x 64 floats = 1024 float4, 4 per thread, fully coalesced
        for (int i4 = t; i4 < PTILE * 16; i4 += 256) {
            int n = n0 + (i4 >> 4);
            float4 v = make_float4(0.f, 0.f, 0.f, 0.f);
            if (n < N) v = *(const float4*)&x[(size_t)n * 64 + (i4 & 15) * 4];
            *(float4*)&xs[i4 * 4] = v;
        }
        __syncthreads();

        float acc[8][8];
#pragma unroll
        for (int i = 0; i < 8; ++i)
#pragma unroll
            for (int c = 0; c < 8; ++c) acc[i][c] = 0.f;

        for (int k = 0; k < 64; k += 4) {
            float wv[4][8];
#pragma unroll
            for (int kk = 0; kk < 4; ++kk) {
                const ushort4 wa = *(const ushort4*)&wl[(k + kk) * 256 + j0];
                const ushort4 wb = *(const ushort4*)&wl[(k + kk) * 256 + j0 + 4];
                wv[kk][0] = bfu(wa.x); wv[kk][1] = bfu(wa.y);
                wv[kk][2] = bfu(wa.z); wv[kk][3] = bfu(wa.w);
                wv[kk][4] = bfu(wb.x); wv[kk][5] = bfu(wb.y);
                wv[kk][6] = bfu(wb.z); wv[kk][7] = bfu(wb.w);
            }
#pragma unroll
            for (int i = 0; i < 8; ++i) {
                const float4 xv = *(const float4*)&xs[(ng * 8 + i) * 64 + k];
#pragma unroll
                for (int c = 0; c < 8; ++c)
                    acc[i][c] += xv.x * wv[0][c] + xv.y * wv[1][c] + xv.z * wv[2][c] + xv.w * wv[3][c];
            }
        }

#pragma unroll
        for (int i = 0; i < 8; ++i) {
            int n = n0 + ng * 8 + i;
            if (n < N) {
                uint2 pk = make_uint2(0u, 0u);
#pragma unroll
                for (int c = 0; c < 4; ++c) {
                    float v = (acc[i][c] + bb[c]) * QSCALE;
                    int q = __float2int_rn(fminf(fmaxf(v, -127.f), 127.f));
                    pk.x |= ((unsigned)(q & 0xff)) << (8 * c);
                }
#pragma unroll
                for (int c = 4; c < 8; ++c) {
                    float v = (acc[i][c] + bb[c]) * QSCALE;
                    int q = __float2int_rn(fminf(fmaxf(v, -127.f), 127.f));
                    pk.y |= ((unsigned)(q & 0xff)) << (8 * (c - 4));
                }
                *(uint2*)(P + (size_t)n * 256 + j0) = pk;
            }
        }
    }
}

// ---------- kernel 2: edge logit (R2-proven exact form, 2048 blocks) — FROZEN ----------
__global__ __launch_bounds__(256) void edge_logit_kernel(
    const unsigned char* __restrict__ P, const int* __restrict__ ei,
    const float* __restrict__ y,
    const float* __restrict__ w2, const float* __restrict__ b2,
    float* __restrict__ elog, unsigned long long* __restrict__ agg, int E)
{
    const int lane = threadIdx.x & 7;
    float w2r[16];
#pragma unroll
    for (int c = 0; c < 16; ++c) w2r[c] = w2[lane * 16 + c] * (1.0f / QSCALE);
    const float b2s = b2[0];

    const int slot = (blockIdx.x * 256 + threadIdx.x) >> 3;
    const int nslots = (gridDim.x * 256) >> 3;
    const int lo16 = lane * 16;

    for (int base = slot * 4; base < E; base += nslots * 4) {
        if (base + 3 < E) {
            const int4 s4 = *(const int4*)&ei[base];
            const int4 d4 = *(const int4*)&ei[E + base];

            const uint4 a0 = *(const uint4*)(P + (size_t)s4.x * 256 + lo16);
            const uint4 b0 = *(const uint4*)(P + (size_t)d4.x * 256 + 128 + lo16);
            const uint4 a1 = *(const uint4*)(P + (size_t)s4.y * 256 + lo16);
            const uint4 b1v = *(const uint4*)(P + (size_t)d4.y * 256 + 128 + lo16);
            const uint4 a2 = *(const uint4*)(P + (size_t)s4.z * 256 + lo16);
            const uint4 b2v = *(const uint4*)(P + (size_t)d4.z * 256 + 128 + lo16);
            const uint4 a3 = *(const uint4*)(P + (size_t)s4.w * 256 + lo16);
            const uint4 b3 = *(const uint4*)(P + (size_t)d4.w * 256 + 128 + lo16);

            const float acc0 = edge_dot(a0, b0, w2r);
            const float acc1 = edge_dot(a1, b1v, w2r);
            const float acc2 = edge_dot(a2, b2v, w2r);
            const float acc3 = edge_dot(a3, b3, w2r);

            if (lane == 0) {
                const float ys0 = y[s4.x];
                const float ys1 = y[s4.y];
                const float ys2 = y[s4.z];
                const float ys3 = y[s4.w];
                const float ev0 = __expf(acc0 + b2s);
                const float ev1 = __expf(acc1 + b2s);
                const float ev2 = __expf(acc2 + b2s);
                const float ev3 = __expf(acc3 + b2s);
                *(float4*)&elog[base] = make_float4(ev0, ev1, ev2, ev3);
                atomicAdd(&agg[d4.x], pack_contrib(ev0, ys0));
                atomicAdd(&agg[d4.y], pack_contrib(ev1, ys1));
                atomicAdd(&agg[d4.z], pack_contrib(ev2, ys2));
                atomicAdd(&agg[d4.w], pack_contrib(ev3, ys3));
            }
        } else {
            for (int e = base; e < E; ++e) {
                const int s = ei[e];
                const int d = ei[E + e];
                const uint4 a = *(const uint4*)(P + (size_t)s * 256 + lo16);
                const uint4 b = *(const uint4*)(P + (size_t)d * 256 + 128 + lo16);
                const float acc = edge_dot(a, b, w2r);
                if (lane == 0) {
                    const float ev = __expf(acc + b2s);
                    elog[e] = ev;
                    atomicAdd(&agg[d], pack_contrib(ev, y[s]));
                }
            }
        }
    }
}

// ---------- kernel 3: fused decode (yhat) + alpha normalize — FROZEN ----------
__global__ __launch_bounds__(256) void decode_alpha_kernel(
    const int* __restrict__ ei, const unsigned long long* __restrict__ agg,
    float* __restrict__ elog, float* __restrict__ yhat, int N, int E)
{
    const int gtid = blockIdx.x * 256 + threadIdx.x;
    const int ntot = gridDim.x * 256;

    for (int i = gtid; i < N; i += ntot) {
        unsigned long long v = agg[i];
        unsigned int lo = (unsigned int)(v & 0xffffffffull);
        int          hi = (int)(v >> 32);
        yhat[i] = (lo != 0u) ? 4.0f * (float)hi / (float)lo : 0.f;   // (hi/2^14)/(lo/2^16)
    }

    for (int base = gtid * 4; base < E; base += ntot * 4) {
        if (base + 3 < E) {
            const int4 d4 = *(const int4*)&ei[E + base];
            float4 ev4 = *(const float4*)&elog[base];
            const unsigned int l0 = (unsigned int)(agg[d4.x] & 0xffffffffull);
            const unsigned int l1 = (unsigned int)(agg[d4.y] & 0xffffffffull);
            const unsigned int l2 = (unsigned int)(agg[d4.z] & 0xffffffffull);
            const unsigned int l3 = (unsigned int)(agg[d4.w] & 0xffffffffull);
            ev4.x = l0 ? ev4.x * (65536.0f / (float)l0) : 0.f;
            ev4.y = l1 ? ev4.y * (65536.0f / (float)l1) : 0.f;
            ev4.z = l2 ? ev4.z * (65536.0f / (float)l2) : 0.f;
            ev4.w = l3 ? ev4.w * (65536.0f / (float)l3) : 0.f;
            *(float4*)&elog[base] = ev4;
        } else {
            for (int e = base; e < E; ++e) {
                const unsigned int lo = (unsigned int)(agg[ei[E + e]] & 0xffffffffull);
                elog[e] = lo ? elog[e] * (65536.0f / (float)lo) : 0.f;
            }
        }
    }
}

extern "C" void kernel_launch(void* const* d_in, const int* in_sizes, int n_in,
                              void* d_out, int out_size, void* d_ws, size_t ws_size,
                              hipStream_t stream) {
    const float* x  = (const float*)d_in[0];
    const float* y  = (const float*)d_in[1];
    const int*   ei = (const int*)d_in[2];
    const float* w1 = (const float*)d_in[3];
    const float* b1 = (const float*)d_in[4];
    const float* w2 = (const float*)d_in[5];
    const float* b2 = (const float*)d_in[6];

    const int N = in_sizes[1];
    const int E = in_sizes[2] / 2;

    float* out  = (float*)d_out;
    float* yhat = out;          // [N]
    float* elog = out + N;      // [E] — exp values, then alpha in place

    char* ws = (char*)d_ws;
    unsigned char* P = (unsigned char*)ws;                         // N*256 int8 = 12.8 MB
    const size_t Pbytes = (size_t)N * 256;
    unsigned long long* agg = (unsigned long long*)(ws + Pbytes);  // N u64

    const int ptiles = (N + PTILE - 1) / PTILE;
    proj_kernel<<<ptiles, 256, 0, stream>>>(x, w1, b1, P, agg, N);
    edge_logit_kernel<<<2048, 256, 0, stream>>>(P, ei, y, w2, b2, elog, agg, E);
    decode_alpha_kernel<<<1600, 256, 0, stream>>>(ei, agg, elog, yhat, N, E);
}

// Round 9
// 200.281 us; speedup vs baseline: 1.8600x; 1.0418x over previous
//
#include <hip/hip_runtime.h>

#define QSCALE 44.0f

// ---------- helpers ----------
// int8 dot over one dword pair: acc += w[i] * relu(a_i + b_i)
__device__ __forceinline__ float dot4_i8(unsigned ax, unsigned bx, const float* w) {
    float acc = 0.f;
#pragma unroll
    for (int i = 0; i < 4; ++i) {
        int va = (int)(char)(ax >> (8 * i));
        int vb = (int)(char)(bx >> (8 * i));
        acc += w[i] * (float)max(va + vb, 0);
    }
    return acc;
}

// full 16-element lane dot + 8-lane reduce -> full 128-dim logit (pre-bias)
__device__ __forceinline__ float edge_dot(const uint4& a, const uint4& b, const float* w2r) {
    float acc;
    acc  = dot4_i8(a.x, b.x, w2r + 0);
    acc += dot4_i8(a.y, b.y, w2r + 4);
    acc += dot4_i8(a.z, b.z, w2r + 8);
    acc += dot4_i8(a.w, b.w, w2r + 12);
    acc += __shfl_xor(acc, 1);
    acc += __shfl_xor(acc, 2);
    acc += __shfl_xor(acc, 4);
    return acc;
}

// packed fixed-point encode: lo = ev*2^16 (u32), hi = y*ev*2^14 (i32)
__device__ __forceinline__ unsigned long long pack_contrib(float ev, float ys) {
    float flo = fminf(ev * 65536.f, 1.0e9f);
    float fhi = fmaxf(fminf(ys * ev * 16384.f, 1.0e9f), -1.0e9f);
    unsigned int qlo = (unsigned int)__float2int_rn(flo);
    int          qhi = __float2int_rn(fhi);
    return ((unsigned long long)(unsigned int)qhi << 32) | (unsigned long long)qlo;
}

__device__ __forceinline__ int q8(float v) {
    return __float2int_rn(fminf(fmaxf(v * QSCALE, -127.f), 127.f)) & 0xff;
}

// ---------- kernel 1: node projection v3b — scalar-operand weight stream, runtime k-loop ----------
// Block = 256 threads = 64 nodes x 4 j-groups. j0 forced wave-uniform via readfirstlane so
// the w1 row address is scalar -> s_load weight stream (SGPR operand port, zero VALU cost).
// x staged in padded LDS (stride 65: banks (node+k)%32, 2-way aliasing = free).
// Per thread: 64 iterations x {1 ds_read_b32 + 64 v_fmac_f32}. No unroll explosion.
__global__ __launch_bounds__(256) void proj_kernel(
    const float* __restrict__ x, const float* __restrict__ w1, const float* __restrict__ b1,
    unsigned char* __restrict__ P, unsigned long long* __restrict__ agg, int N)
{
    __shared__ float xs[64 * 65];                 // 16.6 KB
    const int t = threadIdx.x;
    const int nloc = t & 63;
    const int n = blockIdx.x * 64 + nloc;
    const int j0 = __builtin_amdgcn_readfirstlane((t >> 6) * 32);   // wave-uniform -> SGPR

    if (t < 64) {
        int nn = blockIdx.x * 64 + t;
        if (nn < N) agg[nn] = 0ull;
    }

    // stage x: 64 rows x 64 floats, coalesced float4 loads, padded stores
    for (int i4 = t; i4 < 64 * 16; i4 += 256) {
        const int row = i4 >> 4, c4 = (i4 & 15) * 4;
        const int nn = blockIdx.x * 64 + row;
        float4 v = make_float4(0.f, 0.f, 0.f, 0.f);
        if (nn < N) v = *(const float4*)&x[(size_t)nn * 64 + c4];
        float* d = &xs[row * 65 + c4];
        d[0] = v.x; d[1] = v.y; d[2] = v.z; d[3] = v.w;
    }
    __syncthreads();

    float accA[32], accB[32];
#pragma unroll
    for (int c = 0; c < 32; ++c) { accA[c] = b1[j0 + c]; accB[c] = 0.f; }

    const float* __restrict__ xrow = &xs[nloc * 65];
    for (int k = 0; k < 64; ++k) {
        const float xv = xrow[k];
        const float* __restrict__ wa = w1 + k * 128 + j0;          // uniform -> s_load
        const float* __restrict__ wb = w1 + (64 + k) * 128 + j0;   // uniform -> s_load
#pragma unroll
        for (int c = 0; c < 32; ++c) {
            accA[c] = fmaf(xv, wa[c], accA[c]);
            accB[c] = fmaf(xv, wb[c], accB[c]);
        }
    }

    if (n < N) {
        unsigned dwA[8], dwB[8];
#pragma unroll
        for (int d = 0; d < 8; ++d) {
            dwA[d] = (unsigned)q8(accA[d * 4 + 0])
                   | ((unsigned)q8(accA[d * 4 + 1]) << 8)
                   | ((unsigned)q8(accA[d * 4 + 2]) << 16)
                   | ((unsigned)q8(accA[d * 4 + 3]) << 24);
            dwB[d] = (unsigned)q8(accB[d * 4 + 0])
                   | ((unsigned)q8(accB[d * 4 + 1]) << 8)
                   | ((unsigned)q8(accB[d * 4 + 2]) << 16)
                   | ((unsigned)q8(accB[d * 4 + 3]) << 24);
        }
        unsigned char* pA = P + (size_t)n * 256 + j0;
        unsigned char* pB = P + (size_t)n * 256 + 128 + j0;
        *(uint4*)(pA)      = make_uint4(dwA[0], dwA[1], dwA[2], dwA[3]);
        *(uint4*)(pA + 16) = make_uint4(dwA[4], dwA[5], dwA[6], dwA[7]);
        *(uint4*)(pB)      = make_uint4(dwB[0], dwB[1], dwB[2], dwB[3]);
        *(uint4*)(pB + 16) = make_uint4(dwB[4], dwB[5], dwB[6], dwB[7]);
    }
}

// ---------- kernel 2: edge logit (R2-proven exact form, 2048 blocks) — FROZEN ----------
__global__ __launch_bounds__(256) void edge_logit_kernel(
    const unsigned char* __restrict__ P, const int* __restrict__ ei,
    const float* __restrict__ y,
    const float* __restrict__ w2, const float* __restrict__ b2,
    float* __restrict__ elog, unsigned long long* __restrict__ agg, int E)
{
    const int lane = threadIdx.x & 7;
    float w2r[16];
#pragma unroll
    for (int c = 0; c < 16; ++c) w2r[c] = w2[lane * 16 + c] * (1.0f / QSCALE);
    const float b2s = b2[0];

    const int slot = (blockIdx.x * 256 + threadIdx.x) >> 3;
    const int nslots = (gridDim.x * 256) >> 3;
    const int lo16 = lane * 16;

    for (int base = slot * 4; base < E; base += nslots * 4) {
        if (base + 3 < E) {
            const int4 s4 = *(const int4*)&ei[base];
            const int4 d4 = *(const int4*)&ei[E + base];

            const uint4 a0 = *(const uint4*)(P + (size_t)s4.x * 256 + lo16);
            const uint4 b0 = *(const uint4*)(P + (size_t)d4.x * 256 + 128 + lo16);
            const uint4 a1 = *(const uint4*)(P + (size_t)s4.y * 256 + lo16);
            const uint4 b1v = *(const uint4*)(P + (size_t)d4.y * 256 + 128 + lo16);
            const uint4 a2 = *(const uint4*)(P + (size_t)s4.z * 256 + lo16);
            const uint4 b2v = *(const uint4*)(P + (size_t)d4.z * 256 + 128 + lo16);
            const uint4 a3 = *(const uint4*)(P + (size_t)s4.w * 256 + lo16);
            const uint4 b3 = *(const uint4*)(P + (size_t)d4.w * 256 + 128 + lo16);

            const float acc0 = edge_dot(a0, b0, w2r);
            const float acc1 = edge_dot(a1, b1v, w2r);
            const float acc2 = edge_dot(a2, b2v, w2r);
            const float acc3 = edge_dot(a3, b3, w2r);

            if (lane == 0) {
                const float ys0 = y[s4.x];
                const float ys1 = y[s4.y];
                const float ys2 = y[s4.z];
                const float ys3 = y[s4.w];
                const float ev0 = __expf(acc0 + b2s);
                const float ev1 = __expf(acc1 + b2s);
                const float ev2 = __expf(acc2 + b2s);
                const float ev3 = __expf(acc3 + b2s);
                *(float4*)&elog[base] = make_float4(ev0, ev1, ev2, ev3);
                atomicAdd(&agg[d4.x], pack_contrib(ev0, ys0));
                atomicAdd(&agg[d4.y], pack_contrib(ev1, ys1));
                atomicAdd(&agg[d4.z], pack_contrib(ev2, ys2));
                atomicAdd(&agg[d4.w], pack_contrib(ev3, ys3));
            }
        } else {
            for (int e = base; e < E; ++e) {
                const int s = ei[e];
                const int d = ei[E + e];
                const uint4 a = *(const uint4*)(P + (size_t)s * 256 + lo16);
                const uint4 b = *(const uint4*)(P + (size_t)d * 256 + 128 + lo16);
                const float acc = edge_dot(a, b, w2r);
                if (lane == 0) {
                    const float ev = __expf(acc + b2s);
                    elog[e] = ev;
                    atomicAdd(&agg[d], pack_contrib(ev, y[s]));
                }
            }
        }
    }
}

// ---------- kernel 3: fused decode (yhat) + alpha normalize — FROZEN ----------
__global__ __launch_bounds__(256) void decode_alpha_kernel(
    const int* __restrict__ ei, const unsigned long long* __restrict__ agg,
    float* __restrict__ elog, float* __restrict__ yhat, int N, int E)
{
    const int gtid = blockIdx.x * 256 + threadIdx.x;
    const int ntot = gridDim.x * 256;

    for (int i = gtid; i < N; i += ntot) {
        unsigned long long v = agg[i];
        unsigned int lo = (unsigned int)(v & 0xffffffffull);
        int          hi = (int)(v >> 32);
        yhat[i] = (lo != 0u) ? 4.0f * (float)hi / (float)lo : 0.f;   // (hi/2^14)/(lo/2^16)
    }

    for (int base = gtid * 4; base < E; base += ntot * 4) {
        if (base + 3 < E) {
            const int4 d4 = *(const int4*)&ei[E + base];
            float4 ev4 = *(const float4*)&elog[base];
            const unsigned int l0 = (unsigned int)(agg[d4.x] & 0xffffffffull);
            const unsigned int l1 = (unsigned int)(agg[d4.y] & 0xffffffffull);
            const unsigned int l2 = (unsigned int)(agg[d4.z] & 0xffffffffull);
            const unsigned int l3 = (unsigned int)(agg[d4.w] & 0xffffffffull);
            ev4.x = l0 ? ev4.x * (65536.0f / (float)l0) : 0.f;
            ev4.y = l1 ? ev4.y * (65536.0f / (float)l1) : 0.f;
            ev4.z = l2 ? ev4.z * (65536.0f / (float)l2) : 0.f;
            ev4.w = l3 ? ev4.w * (65536.0f / (float)l3) : 0.f;
            *(float4*)&elog[base] = ev4;
        } else {
            for (int e = base; e < E; ++e) {
                const unsigned int lo = (unsigned int)(agg[ei[E + e]] & 0xffffffffull);
                elog[e] = lo ? elog[e] * (65536.0f / (float)lo) : 0.f;
            }
        }
    }
}

extern "C" void kernel_launch(void* const* d_in, const int* in_sizes, int n_in,
                              void* d_out, int out_size, void* d_ws, size_t ws_size,
                              hipStream_t stream) {
    const float* x  = (const float*)d_in[0];
    const float* y  = (const float*)d_in[1];
    const int*   ei = (const int*)d_in[2];
    const float* w1 = (const float*)d_in[3];
    const float* b1 = (const float*)d_in[4];
    const float* w2 = (const float*)d_in[5];
    const float* b2 = (const float*)d_in[6];

    const int N = in_sizes[1];
    const int E = in_sizes[2] / 2;

    float* out  = (float*)d_out;
    float* yhat = out;          // [N]
    float* elog = out + N;      // [E] — exp values, then alpha in place

    char* ws = (char*)d_ws;
    unsigned char* P = (unsigned char*)ws;                         // N*256 int8 = 12.8 MB
    const size_t Pbytes = (size_t)N * 256;
    unsigned long long* agg = (unsigned long long*)(ws + Pbytes);  // N u64

    proj_kernel<<<(N + 63) / 64, 256, 0, stream>>>(x, w1, b1, P, agg, N);
    edge_logit_kernel<<<2048, 256, 0, stream>>>(P, ei, y, w2, b2, elog, agg, E);
    decode_alpha_kernel<<<1600, 256, 0, stream>>>(ei, agg, elog, yhat, N, E);
}

// Round 10
// 198.511 us; speedup vs baseline: 1.8766x; 1.0089x over previous
//
#include <hip/hip_runtime.h>

#define QSCALE 44.0f

// ---------- helpers ----------
__device__ __forceinline__ unsigned short f2bf(float f) {
    unsigned u = __float_as_uint(f);
    unsigned r = (u + 0x7fffu + ((u >> 16) & 1u)) >> 16;   // RNE
    return (unsigned short)r;
}
__device__ __forceinline__ float bfu(unsigned short s) {
    return __uint_as_float(((unsigned)s) << 16);
}

// int8 dot over one dword pair: acc += w[i] * relu(a_i + b_i)
__device__ __forceinline__ float dot4_i8(unsigned ax, unsigned bx, const float* w) {
    float acc = 0.f;
#pragma unroll
    for (int i = 0; i < 4; ++i) {
        int va = (int)(char)(ax >> (8 * i));
        int vb = (int)(char)(bx >> (8 * i));
        acc += w[i] * (float)max(va + vb, 0);
    }
    return acc;
}

// full 16-element lane dot + 8-lane reduce -> full 128-dim logit (pre-bias)
__device__ __forceinline__ float edge_dot(const uint4& a, const uint4& b, const float* w2r) {
    float acc;
    acc  = dot4_i8(a.x, b.x, w2r + 0);
    acc += dot4_i8(a.y, b.y, w2r + 4);
    acc += dot4_i8(a.z, b.z, w2r + 8);
    acc += dot4_i8(a.w, b.w, w2r + 12);
    acc += __shfl_xor(acc, 1);
    acc += __shfl_xor(acc, 2);
    acc += __shfl_xor(acc, 4);
    return acc;
}

// packed fixed-point encode: lo = ev*2^16 (u32), hi = y*ev*2^14 (i32)
__device__ __forceinline__ unsigned long long pack_contrib(float ev, float ys) {
    float flo = fminf(ev * 65536.f, 1.0e9f);
    float fhi = fmaxf(fminf(ys * ev * 16384.f, 1.0e9f), -1.0e9f);
    unsigned int qlo = (unsigned int)__float2int_rn(flo);
    int          qhi = __float2int_rn(fhi);
    return ((unsigned long long)(unsigned int)qhi << 32) | (unsigned long long)qlo;
}

__device__ __forceinline__ int q8(float v) {
    return __float2int_rn(fminf(fmaxf(v * QSCALE, -127.f), 127.f)) & 0xff;
}

// ---------- kernel 1: node projection v3b (R9-proven) — FROZEN ----------
__global__ __launch_bounds__(256) void proj_kernel(
    const float* __restrict__ x, const float* __restrict__ w1, const float* __restrict__ b1,
    unsigned char* __restrict__ P, unsigned long long* __restrict__ agg, int N)
{
    __shared__ float xs[64 * 65];                 // 16.6 KB
    const int t = threadIdx.x;
    const int nloc = t & 63;
    const int n = blockIdx.x * 64 + nloc;
    const int j0 = __builtin_amdgcn_readfirstlane((t >> 6) * 32);   // wave-uniform -> SGPR

    if (t < 64) {
        int nn = blockIdx.x * 64 + t;
        if (nn < N) agg[nn] = 0ull;
    }

    // stage x: 64 rows x 64 floats, coalesced float4 loads, padded stores
    for (int i4 = t; i4 < 64 * 16; i4 += 256) {
        const int row = i4 >> 4, c4 = (i4 & 15) * 4;
        const int nn = blockIdx.x * 64 + row;
        float4 v = make_float4(0.f, 0.f, 0.f, 0.f);
        if (nn < N) v = *(const float4*)&x[(size_t)nn * 64 + c4];
        float* d = &xs[row * 65 + c4];
        d[0] = v.x; d[1] = v.y; d[2] = v.z; d[3] = v.w;
    }
    __syncthreads();

    float accA[32], accB[32];
#pragma unroll
    for (int c = 0; c < 32; ++c) { accA[c] = b1[j0 + c]; accB[c] = 0.f; }

    const float* __restrict__ xrow = &xs[nloc * 65];
    for (int k = 0; k < 64; ++k) {
        const float xv = xrow[k];
        const float* __restrict__ wa = w1 + k * 128 + j0;          // uniform -> s_load
        const float* __restrict__ wb = w1 + (64 + k) * 128 + j0;   // uniform -> s_load
#pragma unroll
        for (int c = 0; c < 32; ++c) {
            accA[c] = fmaf(xv, wa[c], accA[c]);
            accB[c] = fmaf(xv, wb[c], accB[c]);
        }
    }

    if (n < N) {
        unsigned dwA[8], dwB[8];
#pragma unroll
        for (int d = 0; d < 8; ++d) {
            dwA[d] = (unsigned)q8(accA[d * 4 + 0])
                   | ((unsigned)q8(accA[d * 4 + 1]) << 8)
                   | ((unsigned)q8(accA[d * 4 + 2]) << 16)
                   | ((unsigned)q8(accA[d * 4 + 3]) << 24);
            dwB[d] = (unsigned)q8(accB[d * 4 + 0])
                   | ((unsigned)q8(accB[d * 4 + 1]) << 8)
                   | ((unsigned)q8(accB[d * 4 + 2]) << 16)
                   | ((unsigned)q8(accB[d * 4 + 3]) << 24);
        }
        unsigned char* pA = P + (size_t)n * 256 + j0;
        unsigned char* pB = P + (size_t)n * 256 + 128 + j0;
        *(uint4*)(pA)      = make_uint4(dwA[0], dwA[1], dwA[2], dwA[3]);
        *(uint4*)(pA + 16) = make_uint4(dwA[4], dwA[5], dwA[6], dwA[7]);
        *(uint4*)(pB)      = make_uint4(dwB[0], dwB[1], dwB[2], dwB[3]);
        *(uint4*)(pB + 16) = make_uint4(dwB[4], dwB[5], dwB[6], dwB[7]);
    }
}

// ---------- kernel 2: edge logit — R2 form, ev stored as bf16 temp (halved write) ----------
__global__ __launch_bounds__(256) void edge_logit_kernel(
    const unsigned char* __restrict__ P, const int* __restrict__ ei,
    const float* __restrict__ y,
    const float* __restrict__ w2, const float* __restrict__ b2,
    unsigned short* __restrict__ evh, unsigned long long* __restrict__ agg, int E)
{
    const int lane = threadIdx.x & 7;
    float w2r[16];
#pragma unroll
    for (int c = 0; c < 16; ++c) w2r[c] = w2[lane * 16 + c] * (1.0f / QSCALE);
    const float b2s = b2[0];

    const int slot = (blockIdx.x * 256 + threadIdx.x) >> 3;
    const int nslots = (gridDim.x * 256) >> 3;
    const int lo16 = lane * 16;

    for (int base = slot * 4; base < E; base += nslots * 4) {
        if (base + 3 < E) {
            const int4 s4 = *(const int4*)&ei[base];
            const int4 d4 = *(const int4*)&ei[E + base];

            const uint4 a0 = *(const uint4*)(P + (size_t)s4.x * 256 + lo16);
            const uint4 b0 = *(const uint4*)(P + (size_t)d4.x * 256 + 128 + lo16);
            const uint4 a1 = *(const uint4*)(P + (size_t)s4.y * 256 + lo16);
            const uint4 b1v = *(const uint4*)(P + (size_t)d4.y * 256 + 128 + lo16);
            const uint4 a2 = *(const uint4*)(P + (size_t)s4.z * 256 + lo16);
            const uint4 b2v = *(const uint4*)(P + (size_t)d4.z * 256 + 128 + lo16);
            const uint4 a3 = *(const uint4*)(P + (size_t)s4.w * 256 + lo16);
            const uint4 b3 = *(const uint4*)(P + (size_t)d4.w * 256 + 128 + lo16);

            const float acc0 = edge_dot(a0, b0, w2r);
            const float acc1 = edge_dot(a1, b1v, w2r);
            const float acc2 = edge_dot(a2, b2v, w2r);
            const float acc3 = edge_dot(a3, b3, w2r);

            if (lane == 0) {
                const float ys0 = y[s4.x];
                const float ys1 = y[s4.y];
                const float ys2 = y[s4.z];
                const float ys3 = y[s4.w];
                const float ev0 = __expf(acc0 + b2s);
                const float ev1 = __expf(acc1 + b2s);
                const float ev2 = __expf(acc2 + b2s);
                const float ev3 = __expf(acc3 + b2s);
                *(ushort4*)&evh[base] = make_ushort4(f2bf(ev0), f2bf(ev1), f2bf(ev2), f2bf(ev3));
                atomicAdd(&agg[d4.x], pack_contrib(ev0, ys0));
                atomicAdd(&agg[d4.y], pack_contrib(ev1, ys1));
                atomicAdd(&agg[d4.z], pack_contrib(ev2, ys2));
                atomicAdd(&agg[d4.w], pack_contrib(ev3, ys3));
            }
        } else {
            for (int e = base; e < E; ++e) {
                const int s = ei[e];
                const int d = ei[E + e];
                const uint4 a = *(const uint4*)(P + (size_t)s * 256 + lo16);
                const uint4 b = *(const uint4*)(P + (size_t)d * 256 + 128 + lo16);
                const float acc = edge_dot(a, b, w2r);
                if (lane == 0) {
                    const float ev = __expf(acc + b2s);
                    evh[e] = f2bf(ev);
                    atomicAdd(&agg[d], pack_contrib(ev, y[s]));
                }
            }
        }
    }
}

// ---------- kernel 3: decode (yhat) + alpha normalize — bf16 ev in, f32 alpha out ----------
__global__ __launch_bounds__(256) void decode_alpha_kernel(
    const int* __restrict__ ei, const unsigned long long* __restrict__ agg,
    const unsigned short* __restrict__ evh, float* __restrict__ alpha,
    float* __restrict__ yhat, int N, int E)
{
    const int gtid = blockIdx.x * 256 + threadIdx.x;
    const int ntot = gridDim.x * 256;

    for (int i = gtid; i < N; i += ntot) {
        unsigned long long v = agg[i];
        unsigned int lo = (unsigned int)(v & 0xffffffffull);
        int          hi = (int)(v >> 32);
        yhat[i] = (lo != 0u) ? 4.0f * (float)hi / (float)lo : 0.f;   // (hi/2^14)/(lo/2^16)
    }

    for (int base = gtid * 4; base < E; base += ntot * 4) {
        if (base + 3 < E) {
            const int4 d4 = *(const int4*)&ei[E + base];
            const ushort4 eh = *(const ushort4*)&evh[base];
            const unsigned int l0 = (unsigned int)(agg[d4.x] & 0xffffffffull);
            const unsigned int l1 = (unsigned int)(agg[d4.y] & 0xffffffffull);
            const unsigned int l2 = (unsigned int)(agg[d4.z] & 0xffffffffull);
            const unsigned int l3 = (unsigned int)(agg[d4.w] & 0xffffffffull);
            float4 av;
            av.x = l0 ? bfu(eh.x) * (65536.0f / (float)l0) : 0.f;
            av.y = l1 ? bfu(eh.y) * (65536.0f / (float)l1) : 0.f;
            av.z = l2 ? bfu(eh.z) * (65536.0f / (float)l2) : 0.f;
            av.w = l3 ? bfu(eh.w) * (65536.0f / (float)l3) : 0.f;
            *(float4*)&alpha[base] = av;
        } else {
            for (int e = base; e < E; ++e) {
                const unsigned int lo = (unsigned int)(agg[ei[E + e]] & 0xffffffffull);
                alpha[e] = lo ? bfu(evh[e]) * (65536.0f / (float)lo) : 0.f;
            }
        }
    }
}

extern "C" void kernel_launch(void* const* d_in, const int* in_sizes, int n_in,
                              void* d_out, int out_size, void* d_ws, size_t ws_size,
                              hipStream_t stream) {
    const float* x  = (const float*)d_in[0];
    const float* y  = (const float*)d_in[1];
    const int*   ei = (const int*)d_in[2];
    const float* w1 = (const float*)d_in[3];
    const float* b1 = (const float*)d_in[4];
    const float* w2 = (const float*)d_in[5];
    const float* b2 = (const float*)d_in[6];

    const int N = in_sizes[1];
    const int E = in_sizes[2] / 2;

    float* out   = (float*)d_out;
    float* yhat  = out;          // [N]
    float* alpha = out + N;      // [E] — final alpha (f32)

    char* ws = (char*)d_ws;
    unsigned char* P = (unsigned char*)ws;                         // N*256 int8 = 12.8 MB
    const size_t Pbytes = (size_t)N * 256;
    unsigned long long* agg = (unsigned long long*)(ws + Pbytes);  // N u64
    unsigned short* evh = (unsigned short*)(ws + Pbytes + (size_t)N * 8);  // E bf16 = 3.2 MB

    proj_kernel<<<(N + 63) / 64, 256, 0, stream>>>(x, w1, b1, P, agg, N);
    edge_logit_kernel<<<2048, 256, 0, stream>>>(P, ei, y, w2, b2, evh, agg, E);
    decode_alpha_kernel<<<1600, 256, 0, stream>>>(ei, agg, evh, alpha, yhat, N, E);
}

// Round 11
// 197.146 us; speedup vs baseline: 1.8896x; 1.0069x over previous
//
#include <hip/hip_runtime.h>

#define QSCALE 44.0f

// ---------- helpers ----------
__device__ __forceinline__ unsigned short f2bf(float f) {
    unsigned u = __float_as_uint(f);
    unsigned r = (u + 0x7fffu + ((u >> 16) & 1u)) >> 16;   // RNE
    return (unsigned short)r;
}
__device__ __forceinline__ float bfu(unsigned short s) {
    return __uint_as_float(((unsigned)s) << 16);
}

// int8 dot over one dword pair: acc += w[i] * relu(a_i + b_i)
__device__ __forceinline__ float dot4_i8(unsigned ax, unsigned bx, const float* w) {
    float acc = 0.f;
#pragma unroll
    for (int i = 0; i < 4; ++i) {
        int va = (int)(char)(ax >> (8 * i));
        int vb = (int)(char)(bx >> (8 * i));
        acc += w[i] * (float)max(va + vb, 0);
    }
    return acc;
}

// full 16-element lane dot + 8-lane reduce -> full 128-dim logit (pre-bias)
__device__ __forceinline__ float edge_dot(const uint4& a, const uint4& b, const float* w2r) {
    float acc;
    acc  = dot4_i8(a.x, b.x, w2r + 0);
    acc += dot4_i8(a.y, b.y, w2r + 4);
    acc += dot4_i8(a.z, b.z, w2r + 8);
    acc += dot4_i8(a.w, b.w, w2r + 12);
    acc += __shfl_xor(acc, 1);
    acc += __shfl_xor(acc, 2);
    acc += __shfl_xor(acc, 4);
    return acc;
}

// packed fixed-point encode: lo = ev*2^16 (u32), hi = y*ev*2^14 (i32)
__device__ __forceinline__ unsigned long long pack_contrib(float ev, float ys) {
    float flo = fminf(ev * 65536.f, 1.0e9f);
    float fhi = fmaxf(fminf(ys * ev * 16384.f, 1.0e9f), -1.0e9f);
    unsigned int qlo = (unsigned int)__float2int_rn(flo);
    int          qhi = __float2int_rn(fhi);
    return ((unsigned long long)(unsigned int)qhi << 32) | (unsigned long long)qlo;
}

__device__ __forceinline__ int q8(float v) {
    return __float2int_rn(fminf(fmaxf(v * QSCALE, -127.f), 127.f)) & 0xff;
}

// ---------- grid-wide ticket barrier (R3/R5-proven; runtime block count) ----------
__device__ __forceinline__ void grid_sync(unsigned long long* bar, int nblk) {
    __syncthreads();
    if (threadIdx.x == 0) {
        __threadfence();   // release
        unsigned long long t = atomicAdd(bar, 1ull) + 1ull;
        unsigned long long nb = (unsigned long long)nblk;
        unsigned long long target = ((t + nb - 1ull) / nb) * nb;
        while (__hip_atomic_load(bar, __ATOMIC_RELAXED, __HIP_MEMORY_SCOPE_AGENT) < target)
            __builtin_amdgcn_s_sleep(2);
        __threadfence();   // acquire
    }
    __syncthreads();
}

// ---------- edge phase body (R2-proven form, ev->bf16) ----------
__device__ __forceinline__ void edge_phase(
    const unsigned char* __restrict__ P, const int* __restrict__ ei,
    const float* __restrict__ y, const float* __restrict__ w2,
    const float* __restrict__ b2, unsigned short* __restrict__ evh,
    unsigned long long* __restrict__ agg, int E, int gtid, int nthreads)
{
    const int lane = gtid & 7;
    float w2r[16];
#pragma unroll
    for (int c = 0; c < 16; ++c) w2r[c] = w2[lane * 16 + c] * (1.0f / QSCALE);
    const float b2s = b2[0];

    const int slot = gtid >> 3;
    const int nslots = nthreads >> 3;
    const int lo16 = lane * 16;

    for (int base = slot * 4; base < E; base += nslots * 4) {
        if (base + 3 < E) {
            const int4 s4 = *(const int4*)&ei[base];
            const int4 d4 = *(const int4*)&ei[E + base];

            const uint4 a0 = *(const uint4*)(P + (size_t)s4.x * 256 + lo16);
            const uint4 b0 = *(const uint4*)(P + (size_t)d4.x * 256 + 128 + lo16);
            const uint4 a1 = *(const uint4*)(P + (size_t)s4.y * 256 + lo16);
            const uint4 b1v = *(const uint4*)(P + (size_t)d4.y * 256 + 128 + lo16);
            const uint4 a2 = *(const uint4*)(P + (size_t)s4.z * 256 + lo16);
            const uint4 b2v = *(const uint4*)(P + (size_t)d4.z * 256 + 128 + lo16);
            const uint4 a3 = *(const uint4*)(P + (size_t)s4.w * 256 + lo16);
            const uint4 b3 = *(const uint4*)(P + (size_t)d4.w * 256 + 128 + lo16);

            const float acc0 = edge_dot(a0, b0, w2r);
            const float acc1 = edge_dot(a1, b1v, w2r);
            const float acc2 = edge_dot(a2, b2v, w2r);
            const float acc3 = edge_dot(a3, b3, w2r);

            if (lane == 0) {
                const float ys0 = y[s4.x];
                const float ys1 = y[s4.y];
                const float ys2 = y[s4.z];
                const float ys3 = y[s4.w];
                const float ev0 = __expf(acc0 + b2s);
                const float ev1 = __expf(acc1 + b2s);
                const float ev2 = __expf(acc2 + b2s);
                const float ev3 = __expf(acc3 + b2s);
                *(ushort4*)&evh[base] = make_ushort4(f2bf(ev0), f2bf(ev1), f2bf(ev2), f2bf(ev3));
                atomicAdd(&agg[d4.x], pack_contrib(ev0, ys0));
                atomicAdd(&agg[d4.y], pack_contrib(ev1, ys1));
                atomicAdd(&agg[d4.z], pack_contrib(ev2, ys2));
                atomicAdd(&agg[d4.w], pack_contrib(ev3, ys3));
            }
        } else {
            for (int e = base; e < E; ++e) {
                const int s = ei[e];
                const int d = ei[E + e];
                const uint4 a = *(const uint4*)(P + (size_t)s * 256 + lo16);
                const uint4 b = *(const uint4*)(P + (size_t)d * 256 + 128 + lo16);
                const float acc = edge_dot(a, b, w2r);
                if (lane == 0) {
                    const float ev = __expf(acc + b2s);
                    evh[e] = f2bf(ev);
                    atomicAdd(&agg[d], pack_contrib(ev, y[s]));
                }
            }
        }
    }
}

// ---------- decode phase body ----------
__device__ __forceinline__ void decode_phase(
    const int* __restrict__ ei, const unsigned long long* __restrict__ agg,
    const unsigned short* __restrict__ evh, float* __restrict__ alpha,
    float* __restrict__ yhat, int N, int E, int gtid, int ntot)
{
    for (int i = gtid; i < N; i += ntot) {
        unsigned long long v = agg[i];
        unsigned int lo = (unsigned int)(v & 0xffffffffull);
        int          hi = (int)(v >> 32);
        yhat[i] = (lo != 0u) ? 4.0f * (float)hi / (float)lo : 0.f;   // (hi/2^14)/(lo/2^16)
    }

    for (int base = gtid * 4; base < E; base += ntot * 4) {
        if (base + 3 < E) {
            const int4 d4 = *(const int4*)&ei[E + base];
            const ushort4 eh = *(const ushort4*)&evh[base];
            const unsigned int l0 = (unsigned int)(agg[d4.x] & 0xffffffffull);
            const unsigned int l1 = (unsigned int)(agg[d4.y] & 0xffffffffull);
            const unsigned int l2 = (unsigned int)(agg[d4.z] & 0xffffffffull);
            const unsigned int l3 = (unsigned int)(agg[d4.w] & 0xffffffffull);
            float4 av;
            av.x = l0 ? bfu(eh.x) * (65536.0f / (float)l0) : 0.f;
            av.y = l1 ? bfu(eh.y) * (65536.0f / (float)l1) : 0.f;
            av.z = l2 ? bfu(eh.z) * (65536.0f / (float)l2) : 0.f;
            av.w = l3 ? bfu(eh.w) * (65536.0f / (float)l3) : 0.f;
            *(float4*)&alpha[base] = av;
        } else {
            for (int e = base; e < E; ++e) {
                const unsigned int lo = (unsigned int)(agg[ei[E + e]] & 0xffffffffull);
                alpha[e] = lo ? bfu(evh[e]) * (65536.0f / (float)lo) : 0.f;
            }
        }
    }
}

// ---------- kernel 1: node projection v3b (R9-proven) — FROZEN ----------
__global__ __launch_bounds__(256) void proj_kernel(
    const float* __restrict__ x, const float* __restrict__ w1, const float* __restrict__ b1,
    unsigned char* __restrict__ P, unsigned long long* __restrict__ agg, int N)
{
    __shared__ float xs[64 * 65];                 // 16.6 KB
    const int t = threadIdx.x;
    const int nloc = t & 63;
    const int n = blockIdx.x * 64 + nloc;
    const int j0 = __builtin_amdgcn_readfirstlane((t >> 6) * 32);   // wave-uniform -> SGPR

    if (t < 64) {
        int nn = blockIdx.x * 64 + t;
        if (nn < N) agg[nn] = 0ull;
    }

    for (int i4 = t; i4 < 64 * 16; i4 += 256) {
        const int row = i4 >> 4, c4 = (i4 & 15) * 4;
        const int nn = blockIdx.x * 64 + row;
        float4 v = make_float4(0.f, 0.f, 0.f, 0.f);
        if (nn < N) v = *(const float4*)&x[(size_t)nn * 64 + c4];
        float* d = &xs[row * 65 + c4];
        d[0] = v.x; d[1] = v.y; d[2] = v.z; d[3] = v.w;
    }
    __syncthreads();

    float accA[32], accB[32];
#pragma unroll
    for (int c = 0; c < 32; ++c) { accA[c] = b1[j0 + c]; accB[c] = 0.f; }

    const float* __restrict__ xrow = &xs[nloc * 65];
    for (int k = 0; k < 64; ++k) {
        const float xv = xrow[k];
        const float* __restrict__ wa = w1 + k * 128 + j0;          // uniform -> s_load
        const float* __restrict__ wb = w1 + (64 + k) * 128 + j0;   // uniform -> s_load
#pragma unroll
        for (int c = 0; c < 32; ++c) {
            accA[c] = fmaf(xv, wa[c], accA[c]);
            accB[c] = fmaf(xv, wb[c], accB[c]);
        }
    }

    if (n < N) {
        unsigned dwA[8], dwB[8];
#pragma unroll
        for (int d = 0; d < 8; ++d) {
            dwA[d] = (unsigned)q8(accA[d * 4 + 0])
                   | ((unsigned)q8(accA[d * 4 + 1]) << 8)
                   | ((unsigned)q8(accA[d * 4 + 2]) << 16)
                   | ((unsigned)q8(accA[d * 4 + 3]) << 24);
            dwB[d] = (unsigned)q8(accB[d * 4 + 0])
                   | ((unsigned)q8(accB[d * 4 + 1]) << 8)
                   | ((unsigned)q8(accB[d * 4 + 2]) << 16)
                   | ((unsigned)q8(accB[d * 4 + 3]) << 24);
        }
        unsigned char* pA = P + (size_t)n * 256 + j0;
        unsigned char* pB = P + (size_t)n * 256 + 128 + j0;
        *(uint4*)(pA)      = make_uint4(dwA[0], dwA[1], dwA[2], dwA[3]);
        *(uint4*)(pA + 16) = make_uint4(dwA[4], dwA[5], dwA[6], dwA[7]);
        *(uint4*)(pB)      = make_uint4(dwB[0], dwB[1], dwB[2], dwB[3]);
        *(uint4*)(pB + 16) = make_uint4(dwB[4], dwB[5], dwB[6], dwB[7]);
    }
}

// ---------- cooperative fused kernel: edge -> [grid sync] -> decode ----------
__global__ __launch_bounds__(256, 8) void edge_decode_coop_kernel(
    const unsigned char* __restrict__ P, const int* __restrict__ ei,
    const float* __restrict__ y, const float* __restrict__ w2,
    const float* __restrict__ b2, unsigned short* __restrict__ evh,
    unsigned long long* __restrict__ agg, unsigned long long* __restrict__ bar,
    float* __restrict__ alpha, float* __restrict__ yhat, int N, int E, int nblk)
{
    const int gtid = blockIdx.x * 256 + threadIdx.x;
    const int nthreads = nblk * 256;
    edge_phase(P, ei, y, w2, b2, evh, agg, E, gtid, nthreads);
    grid_sync(bar, nblk);
    decode_phase(ei, agg, evh, alpha, yhat, N, E, gtid, nthreads);
}

// ---------- fallback kernels (R10-proven exact) ----------
__global__ __launch_bounds__(256) void edge_logit_kernel(
    const unsigned char* __restrict__ P, const int* __restrict__ ei,
    const float* __restrict__ y,
    const float* __restrict__ w2, const float* __restrict__ b2,
    unsigned short* __restrict__ evh, unsigned long long* __restrict__ agg, int E)
{
    const int gtid = blockIdx.x * 256 + threadIdx.x;
    edge_phase(P, ei, y, w2, b2, evh, agg, E, gtid, gridDim.x * 256);
}

__global__ __launch_bounds__(256) void decode_alpha_kernel(
    const int* __restrict__ ei, const unsigned long long* __restrict__ agg,
    const unsigned short* __restrict__ evh, float* __restrict__ alpha,
    float* __restrict__ yhat, int N, int E)
{
    const int gtid = blockIdx.x * 256 + threadIdx.x;
    decode_phase(ei, agg, evh, alpha, yhat, N, E, gtid, gridDim.x * 256);
}

extern "C" void kernel_launch(void* const* d_in, const int* in_sizes, int n_in,
                              void* d_out, int out_size, void* d_ws, size_t ws_size,
                              hipStream_t stream) {
    const float* x  = (const float*)d_in[0];
    const float* y  = (const float*)d_in[1];
    const int*   ei = (const int*)d_in[2];
    const float* w1 = (const float*)d_in[3];
    const float* b1 = (const float*)d_in[4];
    const float* w2 = (const float*)d_in[5];
    const float* b2 = (const float*)d_in[6];

    const int N = in_sizes[1];
    const int E = in_sizes[2] / 2;

    float* out   = (float*)d_out;
    float* yhat  = out;          // [N]
    float* alpha = out + N;      // [E]

    char* ws = (char*)d_ws;
    unsigned long long* bar = (unsigned long long*)ws;                   // 1 u64 (padded 256B)
    unsigned char* P = (unsigned char*)(ws + 256);                       // N*256 int8
    const size_t Pbytes = (size_t)N * 256;
    unsigned long long* agg = (unsigned long long*)(ws + 256 + Pbytes);  // N u64
    unsigned short* evh = (unsigned short*)(ws + 256 + Pbytes + (size_t)N * 8);  // E bf16

    proj_kernel<<<(N + 63) / 64, 256, 0, stream>>>(x, w1, b1, P, agg, N);

    // runtime-validated co-residency for the fused path
    static int maxBlkPerCU = -1;
    if (maxBlkPerCU < 0) {
        hipError_t oe = hipOccupancyMaxActiveBlocksPerMultiprocessor(
            &maxBlkPerCU, (const void*)edge_decode_coop_kernel, 256, 0);
        if (oe != hipSuccess || maxBlkPerCU < 1) maxBlkPerCU = 0;
    }

    if (maxBlkPerCU >= 8) {
        int nblk = 2048;   // 8 blk/CU x 256 CU — full R2-proven edge concurrency
        hipMemsetAsync(bar, 0, 8, stream);
        void* args[] = {(void*)&P, (void*)&ei, (void*)&y, (void*)&w2, (void*)&b2,
                        (void*)&evh, (void*)&agg, (void*)&bar, (void*)&alpha,
                        (void*)&yhat, (void*)&N, (void*)&E, (void*)&nblk};
        hipLaunchCooperativeKernel((void*)edge_decode_coop_kernel,
                                   dim3(nblk), dim3(256), args, 0, stream);
    } else {
        // proven 3-kernel path (R10: 198.5 us)
        edge_logit_kernel<<<2048, 256, 0, stream>>>(P, ei, y, w2, b2, evh, agg, E);
        decode_alpha_kernel<<<1600, 256, 0, stream>>>(ei, agg, evh, alpha, yhat, N, E);
    }
}

// Round 12
// 196.899 us; speedup vs baseline: 1.8919x; 1.0013x over previous
//
#include <hip/hip_runtime.h>

#define QSCALE 44.0f

// ---------- helpers ----------
__device__ __forceinline__ unsigned short f2bf(float f) {
    unsigned u = __float_as_uint(f);
    unsigned r = (u + 0x7fffu + ((u >> 16) & 1u)) >> 16;   // RNE
    return (unsigned short)r;
}
__device__ __forceinline__ float bfu(unsigned short s) {
    return __uint_as_float(((unsigned)s) << 16);
}

// int8 dot over one dword pair: acc += w[i] * relu(a_i + b_i)
__device__ __forceinline__ float dot4_i8(unsigned ax, unsigned bx, const float* w) {
    float acc = 0.f;
#pragma unroll
    for (int i = 0; i < 4; ++i) {
        int va = (int)(char)(ax >> (8 * i));
        int vb = (int)(char)(bx >> (8 * i));
        acc += w[i] * (float)max(va + vb, 0);
    }
    return acc;
}

// full 16-element lane dot + 8-lane reduce -> full 128-dim logit (pre-bias)
__device__ __forceinline__ float edge_dot(const uint4& a, const uint4& b, const float* w2r) {
    float acc;
    acc  = dot4_i8(a.x, b.x, w2r + 0);
    acc += dot4_i8(a.y, b.y, w2r + 4);
    acc += dot4_i8(a.z, b.z, w2r + 8);
    acc += dot4_i8(a.w, b.w, w2r + 12);
    acc += __shfl_xor(acc, 1);
    acc += __shfl_xor(acc, 2);
    acc += __shfl_xor(acc, 4);
    return acc;
}

// packed fixed-point encode: lo = ev*2^16 (u32), hi = y*ev*2^14 (i32)
__device__ __forceinline__ unsigned long long pack_contrib(float ev, float ys) {
    float flo = fminf(ev * 65536.f, 1.0e9f);
    float fhi = fmaxf(fminf(ys * ev * 16384.f, 1.0e9f), -1.0e9f);
    unsigned int qlo = (unsigned int)__float2int_rn(flo);
    int          qhi = __float2int_rn(fhi);
    return ((unsigned long long)(unsigned int)qhi << 32) | (unsigned long long)qlo;
}

__device__ __forceinline__ int q8(float v) {
    return __float2int_rn(fminf(fmaxf(v * QSCALE, -127.f), 127.f)) & 0xff;
}

// ---------- grid-wide ticket barrier (R3/R5/R11-proven; runtime block count) ----------
__device__ __forceinline__ void grid_sync(unsigned long long* bar, int nblk) {
    __syncthreads();
    if (threadIdx.x == 0) {
        __threadfence();   // release
        unsigned long long t = atomicAdd(bar, 1ull) + 1ull;
        unsigned long long nb = (unsigned long long)nblk;
        unsigned long long target = ((t + nb - 1ull) / nb) * nb;
        while (__hip_atomic_load(bar, __ATOMIC_RELAXED, __HIP_MEMORY_SCOPE_AGENT) < target)
            __builtin_amdgcn_s_sleep(2);
        __threadfence();   // acquire
    }
    __syncthreads();
}

// ---------- edge phase body (R2-proven form, ev->bf16) ----------
__device__ __forceinline__ void edge_phase(
    const unsigned char* __restrict__ P, const int* __restrict__ ei,
    const float* __restrict__ y, const float* __restrict__ w2,
    const float* __restrict__ b2, unsigned short* __restrict__ evh,
    unsigned long long* __restrict__ agg, int E, int gtid, int nthreads)
{
    const int lane = gtid & 7;
    float w2r[16];
#pragma unroll
    for (int c = 0; c < 16; ++c) w2r[c] = w2[lane * 16 + c] * (1.0f / QSCALE);
    const float b2s = b2[0];

    const int slot = gtid >> 3;
    const int nslots = nthreads >> 3;
    const int lo16 = lane * 16;

    for (int base = slot * 4; base < E; base += nslots * 4) {
        if (base + 3 < E) {
            const int4 s4 = *(const int4*)&ei[base];
            const int4 d4 = *(const int4*)&ei[E + base];

            const uint4 a0 = *(const uint4*)(P + (size_t)s4.x * 256 + lo16);
            const uint4 b0 = *(const uint4*)(P + (size_t)d4.x * 256 + 128 + lo16);
            const uint4 a1 = *(const uint4*)(P + (size_t)s4.y * 256 + lo16);
            const uint4 b1v = *(const uint4*)(P + (size_t)d4.y * 256 + 128 + lo16);
            const uint4 a2 = *(const uint4*)(P + (size_t)s4.z * 256 + lo16);
            const uint4 b2v = *(const uint4*)(P + (size_t)d4.z * 256 + 128 + lo16);
            const uint4 a3 = *(const uint4*)(P + (size_t)s4.w * 256 + lo16);
            const uint4 b3 = *(const uint4*)(P + (size_t)d4.w * 256 + 128 + lo16);

            const float acc0 = edge_dot(a0, b0, w2r);
            const float acc1 = edge_dot(a1, b1v, w2r);
            const float acc2 = edge_dot(a2, b2v, w2r);
            const float acc3 = edge_dot(a3, b3, w2r);

            if (lane == 0) {
                const float ys0 = y[s4.x];
                const float ys1 = y[s4.y];
                const float ys2 = y[s4.z];
                const float ys3 = y[s4.w];
                const float ev0 = __expf(acc0 + b2s);
                const float ev1 = __expf(acc1 + b2s);
                const float ev2 = __expf(acc2 + b2s);
                const float ev3 = __expf(acc3 + b2s);
                *(ushort4*)&evh[base] = make_ushort4(f2bf(ev0), f2bf(ev1), f2bf(ev2), f2bf(ev3));
                atomicAdd(&agg[d4.x], pack_contrib(ev0, ys0));
                atomicAdd(&agg[d4.y], pack_contrib(ev1, ys1));
                atomicAdd(&agg[d4.z], pack_contrib(ev2, ys2));
                atomicAdd(&agg[d4.w], pack_contrib(ev3, ys3));
            }
        } else {
            for (int e = base; e < E; ++e) {
                const int s = ei[e];
                const int d = ei[E + e];
                const uint4 a = *(const uint4*)(P + (size_t)s * 256 + lo16);
                const uint4 b = *(const uint4*)(P + (size_t)d * 256 + 128 + lo16);
                const float acc = edge_dot(a, b, w2r);
                if (lane == 0) {
                    const float ev = __expf(acc + b2s);
                    evh[e] = f2bf(ev);
                    atomicAdd(&agg[d], pack_contrib(ev, y[s]));
                }
            }
        }
    }
}

// ---------- decode phase body ----------
__device__ __forceinline__ void decode_phase(
    const int* __restrict__ ei, const unsigned long long* __restrict__ agg,
    const unsigned short* __restrict__ evh, float* __restrict__ alpha,
    float* __restrict__ yhat, int N, int E, int gtid, int ntot)
{
    for (int i = gtid; i < N; i += ntot) {
        unsigned long long v = agg[i];
        unsigned int lo = (unsigned int)(v & 0xffffffffull);
        int          hi = (int)(v >> 32);
        yhat[i] = (lo != 0u) ? 4.0f * (float)hi / (float)lo : 0.f;   // (hi/2^14)/(lo/2^16)
    }

    for (int base = gtid * 4; base < E; base += ntot * 4) {
        if (base + 3 < E) {
            const int4 d4 = *(const int4*)&ei[E + base];
            const ushort4 eh = *(const ushort4*)&evh[base];
            const unsigned int l0 = (unsigned int)(agg[d4.x] & 0xffffffffull);
            const unsigned int l1 = (unsigned int)(agg[d4.y] & 0xffffffffull);
            const unsigned int l2 = (unsigned int)(agg[d4.z] & 0xffffffffull);
            const unsigned int l3 = (unsigned int)(agg[d4.w] & 0xffffffffull);
            float4 av;
            av.x = l0 ? bfu(eh.x) * (65536.0f / (float)l0) : 0.f;
            av.y = l1 ? bfu(eh.y) * (65536.0f / (float)l1) : 0.f;
            av.z = l2 ? bfu(eh.z) * (65536.0f / (float)l2) : 0.f;
            av.w = l3 ? bfu(eh.w) * (65536.0f / (float)l3) : 0.f;
            *(float4*)&alpha[base] = av;
        } else {
            for (int e = base; e < E; ++e) {
                const unsigned int lo = (unsigned int)(agg[ei[E + e]] & 0xffffffffull);
                alpha[e] = lo ? bfu(evh[e]) * (65536.0f / (float)lo) : 0.f;
            }
        }
    }
}

// ---------- kernel 1: node projection v3b (R9-proven) — FROZEN ----------
__global__ __launch_bounds__(256) void proj_kernel(
    const float* __restrict__ x, const float* __restrict__ w1, const float* __restrict__ b1,
    unsigned char* __restrict__ P, unsigned long long* __restrict__ agg, int N)
{
    __shared__ float xs[64 * 65];                 // 16.6 KB
    const int t = threadIdx.x;
    const int nloc = t & 63;
    const int n = blockIdx.x * 64 + nloc;
    const int j0 = __builtin_amdgcn_readfirstlane((t >> 6) * 32);   // wave-uniform -> SGPR

    if (t < 64) {
        int nn = blockIdx.x * 64 + t;
        if (nn < N) agg[nn] = 0ull;
    }

    for (int i4 = t; i4 < 64 * 16; i4 += 256) {
        const int row = i4 >> 4, c4 = (i4 & 15) * 4;
        const int nn = blockIdx.x * 64 + row;
        float4 v = make_float4(0.f, 0.f, 0.f, 0.f);
        if (nn < N) v = *(const float4*)&x[(size_t)nn * 64 + c4];
        float* d = &xs[row * 65 + c4];
        d[0] = v.x; d[1] = v.y; d[2] = v.z; d[3] = v.w;
    }
    __syncthreads();

    float accA[32], accB[32];
#pragma unroll
    for (int c = 0; c < 32; ++c) { accA[c] = b1[j0 + c]; accB[c] = 0.f; }

    const float* __restrict__ xrow = &xs[nloc * 65];
    for (int k = 0; k < 64; ++k) {
        const float xv = xrow[k];
        const float* __restrict__ wa = w1 + k * 128 + j0;          // uniform -> s_load
        const float* __restrict__ wb = w1 + (64 + k) * 128 + j0;   // uniform -> s_load
#pragma unroll
        for (int c = 0; c < 32; ++c) {
            accA[c] = fmaf(xv, wa[c], accA[c]);
            accB[c] = fmaf(xv, wb[c], accB[c]);
        }
    }

    if (n < N) {
        unsigned dwA[8], dwB[8];
#pragma unroll
        for (int d = 0; d < 8; ++d) {
            dwA[d] = (unsigned)q8(accA[d * 4 + 0])
                   | ((unsigned)q8(accA[d * 4 + 1]) << 8)
                   | ((unsigned)q8(accA[d * 4 + 2]) << 16)
                   | ((unsigned)q8(accA[d * 4 + 3]) << 24);
            dwB[d] = (unsigned)q8(accB[d * 4 + 0])
                   | ((unsigned)q8(accB[d * 4 + 1]) << 8)
                   | ((unsigned)q8(accB[d * 4 + 2]) << 16)
                   | ((unsigned)q8(accB[d * 4 + 3]) << 24);
        }
        unsigned char* pA = P + (size_t)n * 256 + j0;
        unsigned char* pB = P + (size_t)n * 256 + 128 + j0;
        *(uint4*)(pA)      = make_uint4(dwA[0], dwA[1], dwA[2], dwA[3]);
        *(uint4*)(pA + 16) = make_uint4(dwA[4], dwA[5], dwA[6], dwA[7]);
        *(uint4*)(pB)      = make_uint4(dwB[0], dwB[1], dwB[2], dwB[3]);
        *(uint4*)(pB + 16) = make_uint4(dwB[4], dwB[5], dwB[6], dwB[7]);
    }
}

// ---------- cooperative fused kernel: edge -> [grid sync] -> decode ----------
// Plain launch_bounds(256): natural allocation (~52 VGPR) => 8 blocks/CU fit WITHOUT
// register coercion. R11's (256,8) forced VGPR=32 -> scratch spills (WRITE 53->265MB).
__global__ __launch_bounds__(256) void edge_decode_coop_kernel(
    const unsigned char* __restrict__ P, const int* __restrict__ ei,
    const float* __restrict__ y, const float* __restrict__ w2,
    const float* __restrict__ b2, unsigned short* __restrict__ evh,
    unsigned long long* __restrict__ agg, unsigned long long* __restrict__ bar,
    float* __restrict__ alpha, float* __restrict__ yhat, int N, int E, int nblk)
{
    const int gtid = blockIdx.x * 256 + threadIdx.x;
    const int nthreads = nblk * 256;
    edge_phase(P, ei, y, w2, b2, evh, agg, E, gtid, nthreads);
    grid_sync(bar, nblk);
    decode_phase(ei, agg, evh, alpha, yhat, N, E, gtid, nthreads);
}

// ---------- fallback kernels (R10-proven exact) ----------
__global__ __launch_bounds__(256) void edge_logit_kernel(
    const unsigned char* __restrict__ P, const int* __restrict__ ei,
    const float* __restrict__ y,
    const float* __restrict__ w2, const float* __restrict__ b2,
    unsigned short* __restrict__ evh, unsigned long long* __restrict__ agg, int E)
{
    const int gtid = blockIdx.x * 256 + threadIdx.x;
    edge_phase(P, ei, y, w2, b2, evh, agg, E, gtid, gridDim.x * 256);
}

__global__ __launch_bounds__(256) void decode_alpha_kernel(
    const int* __restrict__ ei, const unsigned long long* __restrict__ agg,
    const unsigned short* __restrict__ evh, float* __restrict__ alpha,
    float* __restrict__ yhat, int N, int E)
{
    const int gtid = blockIdx.x * 256 + threadIdx.x;
    decode_phase(ei, agg, evh, alpha, yhat, N, E, gtid, gridDim.x * 256);
}

extern "C" void kernel_launch(void* const* d_in, const int* in_sizes, int n_in,
                              void* d_out, int out_size, void* d_ws, size_t ws_size,
                              hipStream_t stream) {
    const float* x  = (const float*)d_in[0];
    const float* y  = (const float*)d_in[1];
    const int*   ei = (const int*)d_in[2];
    const float* w1 = (const float*)d_in[3];
    const float* b1 = (const float*)d_in[4];
    const float* w2 = (const float*)d_in[5];
    const float* b2 = (const float*)d_in[6];

    const int N = in_sizes[1];
    const int E = in_sizes[2] / 2;

    float* out   = (float*)d_out;
    float* yhat  = out;          // [N]
    float* alpha = out + N;      // [E]

    char* ws = (char*)d_ws;
    unsigned long long* bar = (unsigned long long*)ws;                   // 1 u64 (padded 256B)
    unsigned char* P = (unsigned char*)(ws + 256);                       // N*256 int8
    const size_t Pbytes = (size_t)N * 256;
    unsigned long long* agg = (unsigned long long*)(ws + 256 + Pbytes);  // N u64
    unsigned short* evh = (unsigned short*)(ws + 256 + Pbytes + (size_t)N * 8);  // E bf16

    proj_kernel<<<(N + 63) / 64, 256, 0, stream>>>(x, w1, b1, P, agg, N);

    // runtime-validated co-residency for the fused path
    static int maxBlkPerCU = -1;
    if (maxBlkPerCU < 0) {
        hipError_t oe = hipOccupancyMaxActiveBlocksPerMultiprocessor(
            &maxBlkPerCU, (const void*)edge_decode_coop_kernel, 256, 0);
        if (oe != hipSuccess || maxBlkPerCU < 1) maxBlkPerCU = 0;
    }

    if (maxBlkPerCU >= 8) {
        int nblk = 2048;   // 8 blk/CU x 256 CU — full R2-proven edge concurrency
        hipMemsetAsync(bar, 0, 8, stream);
        void* args[] = {(void*)&P, (void*)&ei, (void*)&y, (void*)&w2, (void*)&b2,
                        (void*)&evh, (void*)&agg, (void*)&bar, (void*)&alpha,
                        (void*)&yhat, (void*)&N, (void*)&E, (void*)&nblk};
        hipLaunchCooperativeKernel((void*)edge_decode_coop_kernel,
                                   dim3(nblk), dim3(256), args, 0, stream);
    } else {
        // proven 3-kernel path (R10: 198.5 us)
        edge_logit_kernel<<<2048, 256, 0, stream>>>(P, ei, y, w2, b2, evh, agg, E);
        decode_alpha_kernel<<<1600, 256, 0, stream>>>(ei, agg, evh, alpha, yhat, N, E);
    }
}